// Round 3
// baseline (978.584 us; speedup 1.0000x reference)
//
#include <hip/hip_runtime.h>
#include <math.h>

// Problem constants
#define NB 64       // batch
#define NI 2048     // input capsules
#define NK 32       // output capsules
#define ND 16       // in_dim = out_dim

// ---------------------------------------------------------------------------
// Fused routing pass.
// VMODE=0: pass A: s0[b,k,o] = sum_i sum_d x*W  (uniform c folded in later as /32)
// VMODE=1: pass B: v = squash(s0/32);            s1 += softmax_k(<u,v>) * u
// VMODE=2: pass C: v = squash(s0/32)+squash(s1); s2 += softmax_k(<u,v>) * u
//
// Thread map (256 thr): kk = t&31 (capsule k), oh = (t>>5)&1 (o-half),
//                       bq4 = t>>6 (wave id = b-quad). Block covers 16 b, 8 i.
// Grid: 1024 blocks, XCD-swizzled so each XCD owns a contiguous 256-i range
//       with all 4 b-groups co-resident (W slice L2-reuse).
// ---------------------------------------------------------------------------
template<int VMODE>
__global__ __launch_bounds__(256, 3)
void caps_pass(const float* __restrict__ X,    // [64][2048][16]
               const float* __restrict__ Wg,   // [2048][32][16][16]
               const float* __restrict__ S0,   // [64][32][16] (VMODE>=1)
               const float* __restrict__ S1,   // [64][32][16] (VMODE==2)
               float* __restrict__ Sout)       // [64][32][16], atomically accumulated
{
    constexpr int IC = 8;                   // i's per block
    __shared__ float Ws[8192];              // W[i], XOR-swizzled [k][d][o] (32 KB)
    __shared__ float Xs[2048];              // x chunk [ig][d][b] swizzled (8 KB)

    const int t   = threadIdx.x;
    const int kk  = t & 31;
    const int oh  = (t >> 5) & 1;           // o-half: o in [oh*8, oh*8+8)
    const int bq4 = t >> 6;                 // wave id, b-quad

    // XCD-aware block swizzle: wg -> (xcd, ichunk-in-xcd, b-group)
    const int wg     = blockIdx.x;          // 0..1023
    const int xcd    = wg & 7;
    const int slot   = wg >> 3;             // 0..127
    const int ichunk = xcd * 32 + (slot >> 2);   // 0..255
    const int bg     = slot & 3;
    const int i0 = ichunk * IC;
    const int b0 = bg * 16;

    float s_acc[4][8];
#pragma unroll
    for (int bb = 0; bb < 4; ++bb)
#pragma unroll
        for (int o = 0; o < 8; ++o) s_acc[bb][o] = 0.f;

    // ---- v fragments in registers, computed in-block from S buffers ----
    float v_r[4][8];
    if constexpr (VMODE >= 1) {
#pragma unroll
        for (int bb = 0; bb < 4; ++bb) {
            const int b = b0 + bq4 * 4 + bb;
            const float* p0 = S0 + ((size_t)b * NK + kk) * 16 + oh * 8;
            float4 a = *(const float4*)(p0);
            float4 c = *(const float4*)(p0 + 4);
            float val0[8] = {a.x,a.y,a.z,a.w,c.x,c.y,c.z,c.w};
            float sq0 = 0.f;
#pragma unroll
            for (int o = 0; o < 8; ++o) { val0[o] *= (1.0f/32.0f); sq0 = fmaf(val0[o], val0[o], sq0); }
            sq0 += __shfl_xor(sq0, 32);
            const float sc0 = sqrtf(sq0) / (1.0f + sq0);
#pragma unroll
            for (int o = 0; o < 8; ++o) v_r[bb][o] = val0[o] * sc0;
            if constexpr (VMODE == 2) {
                const float* p1 = S1 + ((size_t)b * NK + kk) * 16 + oh * 8;
                float4 a1 = *(const float4*)(p1);
                float4 c1 = *(const float4*)(p1 + 4);
                float val1[8] = {a1.x,a1.y,a1.z,a1.w,c1.x,c1.y,c1.z,c1.w};
                float sq1 = 0.f;
#pragma unroll
                for (int o = 0; o < 8; ++o) sq1 = fmaf(val1[o], val1[o], sq1);
                sq1 += __shfl_xor(sq1, 32);
                const float sc1 = sqrtf(sq1) / (1.0f + sq1);
#pragma unroll
                for (int o = 0; o < 8; ++o) v_r[bb][o] = fmaf(val1[o], sc1, v_r[bb][o]);
            }
        }
    }

    // ---- prefetch W[i0] into registers ----
    float4 wreg[8];
    {
        const float4* wsrc = (const float4*)(Wg + (size_t)i0 * 8192);
#pragma unroll
        for (int j = 0; j < 8; ++j) wreg[j] = wsrc[t + j * 256];
    }

    // ---- stage X chunk: Xs[ig][d][b], XOR-swizzled, broadcast-read layout ----
    {
        const int xb   = t >> 4;            // 0..15 batch
        const int xig  = t & 7;             // 0..7 i-in-chunk
        const int half = (t >> 3) & 1;      // d-half
        const float* xp = X + (size_t)(b0 + xb) * (NI * ND) + (size_t)(i0 + xig) * ND + half * 8;
        float4 f0 = *(const float4*)(xp);
        float4 f1 = *(const float4*)(xp + 4);
        float vals[8] = {f0.x,f0.y,f0.z,f0.w,f1.x,f1.y,f1.z,f1.w};
        const int m = (xig & 7) << 3;
#pragma unroll
        for (int jj = 0; jj < 8; ++jj) {
            const int d = half * 8 + jj;
            Xs[xig * 256 + ((16 * d + xb) ^ m)] = vals[jj];
        }
    }

    for (int ii = 0; ii < IC; ++ii) {
        __syncthreads();   // previous iteration's LDS readers done (and Xs ready gate)

        // ---- write prefetched W regs into LDS (swizzled) ----
#pragma unroll
        for (int j = 0; j < 8; ++j) {
            const int k = (t >> 6) + 4 * j;        // wave-uniform
            ((float4*)Ws)[k * 64 + ((t & 63) ^ (k & 7))] = wreg[j];
        }
        // ---- prefetch next i's W into registers (hidden under compute) ----
        if (ii + 1 < IC) {
            const float4* wsrc = (const float4*)(Wg + (size_t)(i0 + ii + 1) * 8192);
#pragma unroll
            for (int j = 0; j < 8; ++j) wreg[j] = wsrc[t + j * 256];
        }
        __syncthreads();

        // ---- compute u_hat fragments and accumulate ----
        const int xm = (ii & 7) << 3;
        float u[4][8];
        if constexpr (VMODE >= 1) {
#pragma unroll
            for (int bb = 0; bb < 4; ++bb)
#pragma unroll
                for (int o = 0; o < 8; ++o) u[bb][o] = 0.f;
        }
#pragma unroll
        for (int d = 0; d < 16; ++d) {
            // x for this wave's 4 batches: broadcast float4 (same addr all lanes)
            const float4 x4 = *(const float4*)(&Xs[ii * 256 + ((16 * d + 4 * bq4) ^ xm)]);
            float wv[8];
            {
                const float4 wA = ((const float4*)Ws)[kk * 64 + ((d * 4 + oh * 2)     ^ (kk & 7))];
                const float4 wB = ((const float4*)Ws)[kk * 64 + ((d * 4 + oh * 2 + 1) ^ (kk & 7))];
                wv[0]=wA.x; wv[1]=wA.y; wv[2]=wA.z; wv[3]=wA.w;
                wv[4]=wB.x; wv[5]=wB.y; wv[6]=wB.z; wv[7]=wB.w;
            }
            if constexpr (VMODE >= 1) {
#pragma unroll
                for (int o = 0; o < 8; ++o) {
                    u[0][o] = fmaf(x4.x, wv[o], u[0][o]);
                    u[1][o] = fmaf(x4.y, wv[o], u[1][o]);
                    u[2][o] = fmaf(x4.z, wv[o], u[2][o]);
                    u[3][o] = fmaf(x4.w, wv[o], u[3][o]);
                }
            } else {
#pragma unroll
                for (int o = 0; o < 8; ++o) {
                    s_acc[0][o] = fmaf(x4.x, wv[o], s_acc[0][o]);
                    s_acc[1][o] = fmaf(x4.y, wv[o], s_acc[1][o]);
                    s_acc[2][o] = fmaf(x4.z, wv[o], s_acc[2][o]);
                    s_acc[3][o] = fmaf(x4.w, wv[o], s_acc[3][o]);
                }
            }
        }

        if constexpr (VMODE >= 1) {
#pragma unroll
            for (int bb = 0; bb < 4; ++bb) {
                // logit over full o: own half + partner half (lane^32 = other oh)
                float lg = 0.f;
#pragma unroll
                for (int o = 0; o < 8; ++o) lg = fmaf(u[bb][o], v_r[bb][o], lg);
                lg += __shfl_xor(lg, 32);
                // softmax over kk (32 lanes within each half)
                float m = lg;
#pragma unroll
                for (int mask = 16; mask >= 1; mask >>= 1)
                    m = fmaxf(m, __shfl_xor(m, mask));
                const float e = __expf(lg - m);
                float ssum = e;
#pragma unroll
                for (int mask = 16; mask >= 1; mask >>= 1)
                    ssum += __shfl_xor(ssum, mask);
                const float c = e / ssum;
#pragma unroll
                for (int o = 0; o < 8; ++o)
                    s_acc[bb][o] = fmaf(c, u[bb][o], s_acc[bb][o]);
            }
        }
    }

    // ---- accumulate block partials to global (disjoint per thread within block) ----
#pragma unroll
    for (int bb = 0; bb < 4; ++bb) {
        float* sp = Sout + ((size_t)(b0 + bq4 * 4 + bb) * NK + kk) * 16 + oh * 8;
#pragma unroll
        for (int o = 0; o < 8; ++o) atomicAdd(sp + o, s_acc[bb][o]);
    }
}

// ---------------------------------------------------------------------------
// out = squash(S)  (final output only)
// ---------------------------------------------------------------------------
__global__ __launch_bounds__(256)
void squash_kernel(const float* __restrict__ S, float* __restrict__ Vout)
{
    const int idx = blockIdx.x * 256 + threadIdx.x;   // 0..32767
    float val = S[idx];
    float sq = val * val;
#pragma unroll
    for (int mask = 8; mask >= 1; mask >>= 1) sq += __shfl_xor(sq, mask);
    const float sc = sqrtf(sq) / (1.0f + sq);
    Vout[idx] = val * sc;
}

extern "C" void kernel_launch(void* const* d_in, const int* in_sizes, int n_in,
                              void* d_out, int out_size, void* d_ws, size_t ws_size,
                              hipStream_t stream)
{
    const float* X  = (const float*)d_in[0];   // [64][2048][16]
    const float* Wg = (const float*)d_in[1];   // [2048][32][16][16]
    float* out = (float*)d_out;                // [64][32][16]

    float* ws  = (float*)d_ws;
    float* s0  = ws;            // 32768
    float* s1  = ws + 32768;
    float* s2  = ws + 65536;    // total 384 KB

    // zero the three accumulation buffers (graph-capturable)
    hipMemsetAsync(ws, 0, (size_t)3 * 32768 * sizeof(float), stream);

    const dim3 pgrid(1024);
    const dim3 pblk(256);

    // Pass A: s0 = sum_i u_hat
    caps_pass<0><<<pgrid, pblk, 0, stream>>>(X, Wg, nullptr, nullptr, s0);
    // Pass B: v0 = squash(s0/32) in-block; s1 = sum_i softmax_k(<u,v0>) * u_hat
    caps_pass<1><<<pgrid, pblk, 0, stream>>>(X, Wg, s0, nullptr, s1);
    // Pass C: v01 = squash(s0/32)+squash(s1) in-block; s2 = sum_i softmax_k(<u,v01>) * u_hat
    caps_pass<2><<<pgrid, pblk, 0, stream>>>(X, Wg, s0, s1, s2);
    // out = squash(s2)
    squash_kernel<<<dim3(128), pblk, 0, stream>>>(s2, out);
}

// Round 4
// 314.071 us; speedup vs baseline: 3.1158x; 3.1158x over previous
//
#include <hip/hip_runtime.h>
#include <math.h>

// Problem constants
#define NB 64       // batch
#define NI 2048     // input capsules
#define NK 32       // output capsules
#define ND 16       // in_dim = out_dim

#if defined(__has_builtin)
#if __has_builtin(__builtin_amdgcn_global_load_lds)
#define HAVE_GLL 1
#endif
#endif
#ifndef HAVE_GLL
#define HAVE_GLL 0
#endif

// ---------------------------------------------------------------------------
// Fused routing pass.
// VMODE=0: pass A: s[b,k,o] = sum_i sum_d x*W (uniform c folded in as /32 later)
// VMODE>=1: u=u_hat[b,i,k,:]; lg=<u,v>; c=softmax_k(lg); s += c*u
//   ATOMIC=0: v read directly from precomputed V (V_or_S0); s written as
//             per-block partial tile part[slab][8192], slab = bg*256+ichunk.
//   ATOMIC=1 (fallback): v computed in-block from S0 (VMODE=1: squash(S0/32);
//             VMODE=2: squash(S0/32)+squash(S1)); s accumulated via atomicAdd.
//
// Thread map (256 thr): kk=t&31, oh=(t>>5)&1 (o-half), bq4=t>>6 (b-quad wave).
// Block covers 16 b x 8 i. Grid 1024, XCD-swizzled (W-slice L2 reuse).
// ---------------------------------------------------------------------------
template<int VMODE, int ATOMIC>
__global__ __launch_bounds__(256, 4)
void caps_pass(const float* __restrict__ X,      // [64][2048][16]
               const float* __restrict__ Wg,     // [2048][32][16][16]
               const float* __restrict__ V_or_S0,
               const float* __restrict__ S1,
               float* __restrict__ Out)          // partial buffer or S accum
{
    constexpr int IC = 8;                   // i's per block
    __shared__ float Ws[8192];              // W[i], XOR-swizzled [k][d][o] (32 KB)
    __shared__ float Xs[2048];              // x chunk [ig][d][b] swizzled (8 KB)

    const int t   = threadIdx.x;
    const int kk  = t & 31;
    const int oh  = (t >> 5) & 1;           // o-half
    const int bq4 = t >> 6;                 // wave id = b-quad

    // XCD-aware block swizzle
    const int wg     = blockIdx.x;          // 0..1023
    const int xcd    = wg & 7;
    const int slot   = wg >> 3;             // 0..127
    const int ichunk = xcd * 32 + (slot >> 2);   // 0..255
    const int bg     = slot & 3;
    const int i0 = ichunk * IC;
    const int b0 = bg * 16;

    float s_acc[4][8];
#pragma unroll
    for (int bb = 0; bb < 4; ++bb)
#pragma unroll
        for (int o = 0; o < 8; ++o) s_acc[bb][o] = 0.f;

    // ---- v fragments in registers (constant over i) ----
    float v_r[4][8];
    if constexpr (VMODE >= 1) {
        if constexpr (ATOMIC == 0) {
            // v precomputed by reduce kernel: direct load
#pragma unroll
            for (int bb = 0; bb < 4; ++bb) {
                const float* vp = V_or_S0 + ((size_t)(b0 + bq4 * 4 + bb) * NK + kk) * 16 + oh * 8;
                float4 a = *(const float4*)(vp);
                float4 c = *(const float4*)(vp + 4);
                v_r[bb][0]=a.x; v_r[bb][1]=a.y; v_r[bb][2]=a.z; v_r[bb][3]=a.w;
                v_r[bb][4]=c.x; v_r[bb][5]=c.y; v_r[bb][6]=c.z; v_r[bb][7]=c.w;
            }
        } else {
            // fallback: squash S buffers in-block (R1-style)
#pragma unroll
            for (int bb = 0; bb < 4; ++bb) {
                const int b = b0 + bq4 * 4 + bb;
                const float* p0 = V_or_S0 + ((size_t)b * NK + kk) * 16 + oh * 8;
                float4 a = *(const float4*)(p0);
                float4 c = *(const float4*)(p0 + 4);
                float val0[8] = {a.x,a.y,a.z,a.w,c.x,c.y,c.z,c.w};
                float sq0 = 0.f;
#pragma unroll
                for (int o = 0; o < 8; ++o) { val0[o] *= (1.0f/32.0f); sq0 = fmaf(val0[o], val0[o], sq0); }
                sq0 += __shfl_xor(sq0, 32);
                const float sc0 = sqrtf(sq0) / (1.0f + sq0);
#pragma unroll
                for (int o = 0; o < 8; ++o) v_r[bb][o] = val0[o] * sc0;
                if constexpr (VMODE == 2) {
                    const float* p1 = S1 + ((size_t)b * NK + kk) * 16 + oh * 8;
                    float4 a1 = *(const float4*)(p1);
                    float4 c1 = *(const float4*)(p1 + 4);
                    float val1[8] = {a1.x,a1.y,a1.z,a1.w,c1.x,c1.y,c1.z,c1.w};
                    float sq1 = 0.f;
#pragma unroll
                    for (int o = 0; o < 8; ++o) sq1 = fmaf(val1[o], val1[o], sq1);
                    sq1 += __shfl_xor(sq1, 32);
                    const float sc1 = sqrtf(sq1) / (1.0f + sq1);
#pragma unroll
                    for (int o = 0; o < 8; ++o) v_r[bb][o] = fmaf(val1[o], sc1, v_r[bb][o]);
                }
            }
        }
    }

    // ---- stage X chunk: Xs[ig][d][b], XOR-swizzled, broadcast-read layout ----
    {
        const int xb   = t >> 4;            // 0..15 batch
        const int xig  = t & 7;             // 0..7 i-in-chunk
        const int half = (t >> 3) & 1;      // d-half
        const float* xp = X + (size_t)(b0 + xb) * (NI * ND) + (size_t)(i0 + xig) * ND + half * 8;
        float4 f0 = *(const float4*)(xp);
        float4 f1 = *(const float4*)(xp + 4);
        float vals[8] = {f0.x,f0.y,f0.z,f0.w,f1.x,f1.y,f1.z,f1.w};
        const int m = (xig & 7) << 3;
#pragma unroll
        for (int jj = 0; jj < 8; ++jj) {
            const int d = half * 8 + jj;
            Xs[xig * 256 + ((16 * d + xb) ^ m)] = vals[jj];
        }
    }

    for (int ii = 0; ii < IC; ++ii) {
        const int i = i0 + ii;
        __syncthreads();   // prev-iter LDS readers done; also gates Xs on ii=0

        // ---- stage W[i] into LDS. Swizzle applied on the GLOBAL source so the
        //      LDS destination stays linear (global_load_lds requirement). ----
#if HAVE_GLL
        {
            const int l  = t & 63;
            const int wv = t >> 6;          // wave-uniform
#pragma unroll
            for (int j = 0; j < 8; ++j) {
                const int k = wv + 4 * j;   // wave-uniform
                const float* gsrc = Wg + (size_t)i * 8192 + k * 256 + 4 * (l ^ (k & 7));
                __builtin_amdgcn_global_load_lds(
                    (const __attribute__((address_space(1))) void*)gsrc,
                    (__attribute__((address_space(3))) void*)&Ws[k * 256],
                    16, 0, 0);
            }
        }
#else
        {
            const float4* wsrc = (const float4*)(Wg + (size_t)i * 8192);
#pragma unroll
            for (int j = 0; j < 8; ++j) {
                float4 val = wsrc[t + j * 256];          // coalesced (transient regs)
                const int k = (t >> 6) + 4 * j;          // wave-uniform
                ((float4*)Ws)[k * 64 + ((t & 63) ^ (k & 7))] = val;
            }
        }
#endif
        __syncthreads();   // waits vmcnt(0): W tile landed

        // ---- compute u_hat fragments and accumulate ----
        const int xm = (ii & 7) << 3;
        float u[4][8];
        if constexpr (VMODE >= 1) {
#pragma unroll
            for (int bb = 0; bb < 4; ++bb)
#pragma unroll
                for (int o = 0; o < 8; ++o) u[bb][o] = 0.f;
        }
#pragma unroll
        for (int d = 0; d < 16; ++d) {
            // x for this wave's 4 batches: broadcast float4 (same addr all lanes)
            const float4 x4 = *(const float4*)(&Xs[ii * 256 + ((16 * d + 4 * bq4) ^ xm)]);
            float wv[8];
            {
                const float4 wA = ((const float4*)Ws)[kk * 64 + ((d * 4 + oh * 2)     ^ (kk & 7))];
                const float4 wB = ((const float4*)Ws)[kk * 64 + ((d * 4 + oh * 2 + 1) ^ (kk & 7))];
                wv[0]=wA.x; wv[1]=wA.y; wv[2]=wA.z; wv[3]=wA.w;
                wv[4]=wB.x; wv[5]=wB.y; wv[6]=wB.z; wv[7]=wB.w;
            }
            if constexpr (VMODE >= 1) {
#pragma unroll
                for (int o = 0; o < 8; ++o) {
                    u[0][o] = fmaf(x4.x, wv[o], u[0][o]);
                    u[1][o] = fmaf(x4.y, wv[o], u[1][o]);
                    u[2][o] = fmaf(x4.z, wv[o], u[2][o]);
                    u[3][o] = fmaf(x4.w, wv[o], u[3][o]);
                }
            } else {
#pragma unroll
                for (int o = 0; o < 8; ++o) {
                    s_acc[0][o] = fmaf(x4.x, wv[o], s_acc[0][o]);
                    s_acc[1][o] = fmaf(x4.y, wv[o], s_acc[1][o]);
                    s_acc[2][o] = fmaf(x4.z, wv[o], s_acc[2][o]);
                    s_acc[3][o] = fmaf(x4.w, wv[o], s_acc[3][o]);
                }
            }
        }

        if constexpr (VMODE >= 1) {
#pragma unroll
            for (int bb = 0; bb < 4; ++bb) {
                float lg = 0.f;
#pragma unroll
                for (int o = 0; o < 8; ++o) lg = fmaf(u[bb][o], v_r[bb][o], lg);
                lg += __shfl_xor(lg, 32);            // other o-half
                float m = lg;
#pragma unroll
                for (int mask = 16; mask >= 1; mask >>= 1)
                    m = fmaxf(m, __shfl_xor(m, mask));
                const float e = __expf(lg - m);
                float ssum = e;
#pragma unroll
                for (int mask = 16; mask >= 1; mask >>= 1)
                    ssum += __shfl_xor(ssum, mask);
                const float c = e / ssum;
#pragma unroll
                for (int o = 0; o < 8; ++o)
                    s_acc[bb][o] = fmaf(c, u[bb][o], s_acc[bb][o]);
            }
        }
    }

    // ---- epilogue ----
    if constexpr (ATOMIC == 0) {
        // contiguous per-block partial tile: part[slab][16b][32k][16o]
        const int slab = bg * 256 + ichunk;
        float4* p4 = (float4*)(Out + (size_t)slab * 8192);
#pragma unroll
        for (int bb = 0; bb < 4; ++bb) {
            const int off = ((bq4 * 4 + bb) * 512 + kk * 16 + oh * 8) >> 2;
            float4 st0 = {s_acc[bb][0], s_acc[bb][1], s_acc[bb][2], s_acc[bb][3]};
            float4 st1 = {s_acc[bb][4], s_acc[bb][5], s_acc[bb][6], s_acc[bb][7]};
            p4[off]     = st0;
            p4[off + 1] = st1;
        }
    } else {
#pragma unroll
        for (int bb = 0; bb < 4; ++bb) {
            float* sp = Out + ((size_t)(b0 + bq4 * 4 + bb) * NK + kk) * 16 + oh * 8;
#pragma unroll
            for (int o = 0; o < 8; ++o) atomicAdd(sp + o, s_acc[bb][o]);
        }
    }
}

// ---------------------------------------------------------------------------
// Reduce 256 partial slabs per output element + fused squash / v production.
// RMODE=0: s0 = sum; store s0; v0 = squash(s0/32)
// RMODE=1: s1 = sum; v01 = squash(S0red/32) + squash(s1)
// RMODE=2: out = squash(sum)
// Grid 512 x 256: block owns 64 outputs; thread (jl=t&63, qc=t>>6) sums 64 ics.
// ---------------------------------------------------------------------------
template<int RMODE>
__global__ __launch_bounds__(256)
void caps_reduce(const float* __restrict__ part,
                 const float* __restrict__ S0red,
                 float* __restrict__ S0out,
                 float* __restrict__ Vout)
{
    __shared__ float red[4][64];
    const int t   = threadIdx.x;
    const int jl  = t & 63;
    const int qc  = t >> 6;
    const int jb  = blockIdx.x * 64;
    const int j   = jb + jl;
    const int bg  = j >> 13;
    const int loc = j & 8191;
    const float* p = part + ((size_t)(bg * 256 + qc * 64)) * 8192 + loc;
    float sum = 0.f;
#pragma unroll 8
    for (int ic = 0; ic < 64; ++ic) sum += p[(size_t)ic * 8192];
    red[qc][jl] = sum;
    __syncthreads();
    if (t < 64) {
        const int jj = jb + t;
        float total = red[0][t] + red[1][t] + red[2][t] + red[3][t];
        if constexpr (RMODE == 0) {
            S0out[jj] = total;
            float val = total * (1.0f / 32.0f);
            float sq = val * val;
#pragma unroll
            for (int mask = 8; mask >= 1; mask >>= 1) sq += __shfl_xor(sq, mask);
            const float sc = sqrtf(sq) / (1.0f + sq);
            Vout[jj] = val * sc;
        } else if constexpr (RMODE == 1) {
            float val0 = S0red[jj] * (1.0f / 32.0f);
            float sq0 = val0 * val0;
#pragma unroll
            for (int mask = 8; mask >= 1; mask >>= 1) sq0 += __shfl_xor(sq0, mask);
            const float sc0 = sqrtf(sq0) / (1.0f + sq0);
            float sq1 = total * total;
#pragma unroll
            for (int mask = 8; mask >= 1; mask >>= 1) sq1 += __shfl_xor(sq1, mask);
            const float sc1 = sqrtf(sq1) / (1.0f + sq1);
            Vout[jj] = fmaf(val0, sc0, total * sc1);
        } else {
            float sq = total * total;
#pragma unroll
            for (int mask = 8; mask >= 1; mask >>= 1) sq += __shfl_xor(sq, mask);
            const float sc = sqrtf(sq) / (1.0f + sq);
            Vout[jj] = total * sc;
        }
    }
}

// ---------------------------------------------------------------------------
// out = squash(S)  (atomic-fallback final only)
// ---------------------------------------------------------------------------
__global__ __launch_bounds__(256)
void squash_kernel(const float* __restrict__ S, float* __restrict__ Vout)
{
    const int idx = blockIdx.x * 256 + threadIdx.x;   // 0..32767
    float val = S[idx];
    float sq = val * val;
#pragma unroll
    for (int mask = 8; mask >= 1; mask >>= 1) sq += __shfl_xor(sq, mask);
    const float sc = sqrtf(sq) / (1.0f + sq);
    Vout[idx] = val * sc;
}

extern "C" void kernel_launch(void* const* d_in, const int* in_sizes, int n_in,
                              void* d_out, int out_size, void* d_ws, size_t ws_size,
                              hipStream_t stream)
{
    const float* X  = (const float*)d_in[0];   // [64][2048][16]
    const float* Wg = (const float*)d_in[1];   // [2048][32][16][16]
    float* out = (float*)d_out;                // [64][32][16]
    float* ws  = (float*)d_ws;

    const size_t PART = (size_t)1024 * 8192;                 // floats
    const size_t need = (PART + 3 * 32768) * sizeof(float);  // ~34 MB

    const dim3 pgrid(1024), blk(256), rgrid(512);

    if (ws_size >= need) {
        // --- partial-reduction path (no atomics, no memset) ---
        float* part = ws;
        float* s0   = ws + PART;
        float* v0   = s0 + 32768;
        float* v01  = v0 + 32768;

        caps_pass<0,0><<<pgrid, blk, 0, stream>>>(X, Wg, nullptr, nullptr, part);
        caps_reduce<0><<<rgrid, blk, 0, stream>>>(part, nullptr, s0, v0);
        caps_pass<1,0><<<pgrid, blk, 0, stream>>>(X, Wg, v0, nullptr, part);
        caps_reduce<1><<<rgrid, blk, 0, stream>>>(part, s0, nullptr, v01);
        caps_pass<1,0><<<pgrid, blk, 0, stream>>>(X, Wg, v01, nullptr, part);
        caps_reduce<2><<<rgrid, blk, 0, stream>>>(part, nullptr, nullptr, out);
    } else {
        // --- atomic fallback (proven R1 structure) ---
        float* s0 = ws;
        float* s1 = ws + 32768;
        float* s2 = ws + 65536;
        hipMemsetAsync(ws, 0, (size_t)3 * 32768 * sizeof(float), stream);
        caps_pass<0,1><<<pgrid, blk, 0, stream>>>(X, Wg, nullptr, nullptr, s0);
        caps_pass<1,1><<<pgrid, blk, 0, stream>>>(X, Wg, s0, nullptr, s1);
        caps_pass<2,1><<<pgrid, blk, 0, stream>>>(X, Wg, s0, s1, s2);
        squash_kernel<<<dim3(128), blk, 0, stream>>>(s2, out);
    }
}

// Round 5
// 178.690 us; speedup vs baseline: 5.4764x; 1.7576x over previous
//
#include <hip/hip_runtime.h>
#include <math.h>
#include <stdint.h>

// Problem constants
#define NB 64       // batch
#define NI 2048     // input capsules
#define NK 32       // output capsules
#define ND 16       // in_dim = out_dim

typedef _Float16 h2t __attribute__((ext_vector_type(2)));

#if defined(__has_builtin)
#if __has_builtin(__builtin_amdgcn_fdot2)
#define USE_FDOT2 1
#endif
#if __has_builtin(__builtin_amdgcn_global_load_lds)
#define HAVE_GLL 1
#endif
#endif
#ifndef USE_FDOT2
#define USE_FDOT2 0
#endif
#ifndef HAVE_GLL
#define HAVE_GLL 0
#endif

static __device__ __forceinline__ float dot2acc(uint32_t w, uint32_t x, float c) {
#if USE_FDOT2
    return __builtin_amdgcn_fdot2(__builtin_bit_cast(h2t, w),
                                  __builtin_bit_cast(h2t, x), c, false);
#else
    h2t wh = __builtin_bit_cast(h2t, w);
    h2t xh = __builtin_bit_cast(h2t, x);
    return fmaf((float)wh.x, (float)xh.x, fmaf((float)wh.y, (float)xh.y, c));
#endif
}

static __device__ __forceinline__ uint32_t pack_h2(float a, float b) {
    h2t p; p.x = (_Float16)a; p.y = (_Float16)b;
    return __builtin_bit_cast(uint32_t, p);
}

// ---------------------------------------------------------------------------
// Convert W f32 [2048][32][16][16] -> f16 d-pair-packed, PRE-SWIZZLED tiles.
// Tile i = 4096 u32; k-block = 128 u32; 16B unit u = o*2+dph holds dp=dph*4..+4
// for output column o. Stored at unit position (u ^ k) so the pass's linear
// global_load_lds + swizzled ds_read_b128 is bank-uniform.
// ---------------------------------------------------------------------------
__global__ __launch_bounds__(256)
void conv_w(const float* __restrict__ Wg, uint32_t* __restrict__ Wh)
{
    const int i = blockIdx.x;          // 0..2047
    const int t = threadIdx.x;
    const int k   = t >> 3;            // 0..31
    const int sub = t & 7;             // 0..7
    const float* src = Wg + (size_t)i * 8192 + k * 256;
    uint4* dst4 = (uint4*)(Wh + (size_t)i * 4096 + k * 128);
#pragma unroll
    for (int uu = 0; uu < 4; ++uu) {
        const int u   = sub * 4 + uu;  // 0..31
        const int o   = u >> 1;
        const int dph = u & 1;
        uint32_t out[4];
#pragma unroll
        for (int pos = 0; pos < 4; ++pos) {
            const int dp = dph * 4 + pos;
            const float a = src[(2 * dp) * 16 + o];
            const float b = src[(2 * dp + 1) * 16 + o];
            out[pos] = pack_h2(a, b);
        }
        uint4 v; v.x = out[0]; v.y = out[1]; v.z = out[2]; v.w = out[3];
        dst4[u ^ k] = v;
    }
}

// ---------------------------------------------------------------------------
// Convert X f32 -> f16 d-pair-packed: XhU[j] = pack(Xflat[2j], Xflat[2j+1]).
// ---------------------------------------------------------------------------
__global__ __launch_bounds__(256)
void conv_x(const float* __restrict__ X, uint32_t* __restrict__ Xh)
{
    const size_t idx = (size_t)blockIdx.x * 256 + threadIdx.x;   // 0..262143
    const float4 f0 = ((const float4*)X)[idx * 2];
    const float4 f1 = ((const float4*)X)[idx * 2 + 1];
    uint4 v;
    v.x = pack_h2(f0.x, f0.y);
    v.y = pack_h2(f0.z, f0.w);
    v.z = pack_h2(f1.x, f1.y);
    v.w = pack_h2(f1.z, f1.w);
    ((uint4*)Xh)[idx] = v;
}

// ---------------------------------------------------------------------------
// f16 fused routing pass (double-buffered W staging via global_load_lds).
// VMODE=0: s[b,k,o] = sum_i sum_d x*W (uniform c folded as /32 in reduce)
// VMODE=1: u=u_hat; lg=<u,V[b,k,:]>; c=softmax_k(lg) (no max-sub; |lg| small);
//          s += c*u.  Partials: part[slab][16b][32k][16o], slab=bg*256+ichunk.
// Thread map: kk=t&31, oh=(t>>5)&1, bq4=t>>6. Block = 16 b x 8 i.
// ---------------------------------------------------------------------------
template<int VMODE>
__global__ __launch_bounds__(256, 4)
void caps_pass_h(const uint32_t* __restrict__ Xh,   // [64][2048][8] u32
                 const uint32_t* __restrict__ Wh,   // [2048][4096] u32 tiles
                 const float* __restrict__ V,       // [64][32][16] (VMODE=1)
                 float* __restrict__ part)
{
    constexpr int IC = 8;
    __shared__ uint32_t Ws[2][4096];   // 2 x 16 KB W tiles
    __shared__ uint32_t Xs[1024];      // [ig][dp][16b] 4 KB

    const int t   = threadIdx.x;
    const int kk  = t & 31;
    const int oh  = (t >> 5) & 1;
    const int bq4 = t >> 6;

    const int wg     = blockIdx.x;
    const int xcd    = wg & 7;
    const int slot   = wg >> 3;
    const int ichunk = xcd * 32 + (slot >> 2);   // 0..255
    const int bg     = slot & 3;
    const int i0 = ichunk * IC;
    const int b0 = bg * 16;

    float s_acc[4][8];
#pragma unroll
    for (int bb = 0; bb < 4; ++bb)
#pragma unroll
        for (int oo = 0; oo < 8; ++oo) s_acc[bb][oo] = 0.f;

    float v_r[4][8];
    if constexpr (VMODE == 1) {
#pragma unroll
        for (int bb = 0; bb < 4; ++bb) {
            const float* vp = V + ((size_t)(b0 + bq4 * 4 + bb) * NK + kk) * 16 + oh * 8;
            float4 a = *(const float4*)(vp);
            float4 c = *(const float4*)(vp + 4);
            v_r[bb][0]=a.x; v_r[bb][1]=a.y; v_r[bb][2]=a.z; v_r[bb][3]=a.w;
            v_r[bb][4]=c.x; v_r[bb][5]=c.y; v_r[bb][6]=c.z; v_r[bb][7]=c.w;
        }
    }

    // ---- stage X chunk: Xs[ig][dp][b] ----
    {
        const int xb  = t >> 4;        // 0..15
        const int ig  = (t >> 1) & 7;  // 0..7
        const int dph = t & 1;
        uint4 v = *(const uint4*)(Xh + (size_t)(b0 + xb) * 16384 + (size_t)(i0 + ig) * 8 + dph * 4);
        const int base = ig * 128 + dph * 64 + xb;   // + q*16 for dp=dph*4+q
        Xs[base]      = v.x;
        Xs[base + 16] = v.y;
        Xs[base + 32] = v.z;
        Xs[base + 48] = v.w;
    }

    // ---- prologue: stage W[i0] into buf 0 ----
    const int l  = t & 63;
    const int wv = t >> 6;
#if HAVE_GLL
#pragma unroll
    for (int j = 0; j < 4; ++j) {
        const int p = wv * 4 + j;
        const uint32_t* g = Wh + (size_t)i0 * 4096 + p * 256 + l * 4;
        __builtin_amdgcn_global_load_lds(
            (const __attribute__((address_space(1))) void*)g,
            (__attribute__((address_space(3))) void*)&Ws[0][p * 256], 16, 0, 0);
    }
#else
#pragma unroll
    for (int j = 0; j < 4; ++j) {
        const int p = wv * 4 + j;
        ((uint4*)&Ws[0][p * 256])[l] = *(const uint4*)(Wh + (size_t)i0 * 4096 + p * 256 + l * 4);
    }
#endif

    for (int ii = 0; ii < IC; ++ii) {
        __syncthreads();   // drains staged W for buf[ii&1]; protects prev readers

        // ---- issue next-tile stage into the other buffer (overlaps compute) ----
        if (ii + 1 < IC) {
            const int nxt = (ii + 1) & 1;
            const size_t ibase = (size_t)(i0 + ii + 1) * 4096;
#if HAVE_GLL
#pragma unroll
            for (int j = 0; j < 4; ++j) {
                const int p = wv * 4 + j;
                const uint32_t* g = Wh + ibase + p * 256 + l * 4;
                __builtin_amdgcn_global_load_lds(
                    (const __attribute__((address_space(1))) void*)g,
                    (__attribute__((address_space(3))) void*)&Ws[nxt][p * 256], 16, 0, 0);
            }
#else
#pragma unroll
            for (int j = 0; j < 4; ++j) {
                const int p = wv * 4 + j;
                ((uint4*)&Ws[nxt][p * 256])[l] = *(const uint4*)(Wh + ibase + p * 256 + l * 4);
            }
#endif
        }

        // ---- compute u_hat via packed f16 dot2 ----
        const uint4* W4 = (const uint4*)Ws[ii & 1];
        const uint4* X4 = (const uint4*)Xs;

        float u[4][8];
#pragma unroll
        for (int bb = 0; bb < 4; ++bb)
#pragma unroll
            for (int oo = 0; oo < 8; ++oo) u[bb][oo] = 0.f;

#pragma unroll
        for (int dph = 0; dph < 2; ++dph) {
            const uint4 xq0 = X4[ii * 32 + (dph * 4 + 0) * 4 + bq4];
            const uint4 xq1 = X4[ii * 32 + (dph * 4 + 1) * 4 + bq4];
            const uint4 xq2 = X4[ii * 32 + (dph * 4 + 2) * 4 + bq4];
            const uint4 xq3 = X4[ii * 32 + (dph * 4 + 3) * 4 + bq4];
#pragma unroll
            for (int oo = 0; oo < 8; ++oo) {
                const int un = (((oh * 8 + oo) * 2 + dph) ^ kk);
                const uint4 w4 = W4[kk * 32 + un];
#define DOT_Q(WQ, XQ) \
                u[0][oo] = dot2acc(WQ, XQ.x, u[0][oo]); \
                u[1][oo] = dot2acc(WQ, XQ.y, u[1][oo]); \
                u[2][oo] = dot2acc(WQ, XQ.z, u[2][oo]); \
                u[3][oo] = dot2acc(WQ, XQ.w, u[3][oo]);
                DOT_Q(w4.x, xq0)
                DOT_Q(w4.y, xq1)
                DOT_Q(w4.z, xq2)
                DOT_Q(w4.w, xq3)
#undef DOT_Q
            }
        }

        if constexpr (VMODE == 0) {
#pragma unroll
            for (int bb = 0; bb < 4; ++bb)
#pragma unroll
                for (int oo = 0; oo < 8; ++oo) s_acc[bb][oo] += u[bb][oo];
        } else {
#pragma unroll
            for (int bb = 0; bb < 4; ++bb) {
                float lg = 0.f;
#pragma unroll
                for (int oo = 0; oo < 8; ++oo) lg = fmaf(u[bb][oo], v_r[bb][oo], lg);
                lg += __shfl_xor(lg, 32);            // other o-half
                // |lg| = |<u,v>| is small (|v|<1, |u|~1): exp-safe without max-sub
                const float e = __expf(lg);
                float ssum = e;
#pragma unroll
                for (int mask = 16; mask >= 1; mask >>= 1)
                    ssum += __shfl_xor(ssum, mask);
                const float c = e / ssum;
#pragma unroll
                for (int oo = 0; oo < 8; ++oo)
                    s_acc[bb][oo] = fmaf(c, u[bb][oo], s_acc[bb][oo]);
            }
        }
    }

    // ---- contiguous per-block partial tile ----
    const int slab = bg * 256 + ichunk;
    float4* p4 = (float4*)(part + (size_t)slab * 8192);
#pragma unroll
    for (int bb = 0; bb < 4; ++bb) {
        const int off = ((bq4 * 4 + bb) * 512 + kk * 16 + oh * 8) >> 2;
        float4 st0 = {s_acc[bb][0], s_acc[bb][1], s_acc[bb][2], s_acc[bb][3]};
        float4 st1 = {s_acc[bb][4], s_acc[bb][5], s_acc[bb][6], s_acc[bb][7]};
        p4[off]     = st0;
        p4[off + 1] = st1;
    }
}

// ---------------------------------------------------------------------------
// Reduce 256 partial slabs per output element + fused squash / v production.
// RMODE=0: s0 = sum; store s0; v0 = squash(s0/32)
// RMODE=1: v01 = squash(S0red/32) + squash(sum)
// RMODE=2: out = squash(sum)
// ---------------------------------------------------------------------------
template<int RMODE>
__global__ __launch_bounds__(256)
void caps_reduce(const float* __restrict__ part,
                 const float* __restrict__ S0red,
                 float* __restrict__ S0out,
                 float* __restrict__ Vout)
{
    __shared__ float red[4][64];
    const int t   = threadIdx.x;
    const int jl  = t & 63;
    const int qc  = t >> 6;
    const int jb  = blockIdx.x * 64;
    const int j   = jb + jl;
    const int bg  = j >> 13;
    const int loc = j & 8191;
    const float* p = part + ((size_t)(bg * 256 + qc * 64)) * 8192 + loc;
    float sum = 0.f;
#pragma unroll 8
    for (int ic = 0; ic < 64; ++ic) sum += p[(size_t)ic * 8192];
    red[qc][jl] = sum;
    __syncthreads();
    if (t < 64) {
        const int jj = jb + t;
        float total = red[0][t] + red[1][t] + red[2][t] + red[3][t];
        if constexpr (RMODE == 0) {
            S0out[jj] = total;
            float val = total * (1.0f / 32.0f);
            float sq = val * val;
#pragma unroll
            for (int mask = 8; mask >= 1; mask >>= 1) sq += __shfl_xor(sq, mask);
            const float sc = sqrtf(sq) / (1.0f + sq);
            Vout[jj] = val * sc;
        } else if constexpr (RMODE == 1) {
            float val0 = S0red[jj] * (1.0f / 32.0f);
            float sq0 = val0 * val0;
#pragma unroll
            for (int mask = 8; mask >= 1; mask >>= 1) sq0 += __shfl_xor(sq0, mask);
            const float sc0 = sqrtf(sq0) / (1.0f + sq0);
            float sq1 = total * total;
#pragma unroll
            for (int mask = 8; mask >= 1; mask >>= 1) sq1 += __shfl_xor(sq1, mask);
            const float sc1 = sqrtf(sq1) / (1.0f + sq1);
            Vout[jj] = fmaf(val0, sc0, total * sc1);
        } else {
            float sq = total * total;
#pragma unroll
            for (int mask = 8; mask >= 1; mask >>= 1) sq += __shfl_xor(sq, mask);
            const float sc = sqrtf(sq) / (1.0f + sq);
            Vout[jj] = total * sc;
        }
    }
}

// ===========================================================================
// Fallback (small ws): proven R1-style f32 atomic path.
// ===========================================================================
template<int VMODE>
__global__ __launch_bounds__(256, 4)
void caps_pass_f32(const float* __restrict__ X,
                   const float* __restrict__ Wg,
                   const float* __restrict__ S0,
                   const float* __restrict__ S1,
                   float* __restrict__ Sout)
{
    constexpr int IC = 8;
    __shared__ float Ws[8192];
    __shared__ float Xs[2048];

    const int t   = threadIdx.x;
    const int kk  = t & 31;
    const int oh  = (t >> 5) & 1;
    const int bq4 = t >> 6;

    const int wg     = blockIdx.x;
    const int xcd    = wg & 7;
    const int slot   = wg >> 3;
    const int ichunk = xcd * 32 + (slot >> 2);
    const int bg     = slot & 3;
    const int i0 = ichunk * IC;
    const int b0 = bg * 16;

    float s_acc[4][8];
#pragma unroll
    for (int bb = 0; bb < 4; ++bb)
#pragma unroll
        for (int o = 0; o < 8; ++o) s_acc[bb][o] = 0.f;

    float v_r[4][8];
    if constexpr (VMODE >= 1) {
#pragma unroll
        for (int bb = 0; bb < 4; ++bb) {
            const int b = b0 + bq4 * 4 + bb;
            const float* p0 = S0 + ((size_t)b * NK + kk) * 16 + oh * 8;
            float4 a = *(const float4*)(p0);
            float4 c = *(const float4*)(p0 + 4);
            float val0[8] = {a.x,a.y,a.z,a.w,c.x,c.y,c.z,c.w};
            float sq0 = 0.f;
#pragma unroll
            for (int o = 0; o < 8; ++o) { val0[o] *= (1.0f/32.0f); sq0 = fmaf(val0[o], val0[o], sq0); }
            sq0 += __shfl_xor(sq0, 32);
            const float sc0 = sqrtf(sq0) / (1.0f + sq0);
#pragma unroll
            for (int o = 0; o < 8; ++o) v_r[bb][o] = val0[o] * sc0;
            if constexpr (VMODE == 2) {
                const float* p1 = S1 + ((size_t)b * NK + kk) * 16 + oh * 8;
                float4 a1 = *(const float4*)(p1);
                float4 c1 = *(const float4*)(p1 + 4);
                float val1[8] = {a1.x,a1.y,a1.z,a1.w,c1.x,c1.y,c1.z,c1.w};
                float sq1 = 0.f;
#pragma unroll
                for (int o = 0; o < 8; ++o) sq1 = fmaf(val1[o], val1[o], sq1);
                sq1 += __shfl_xor(sq1, 32);
                const float sc1 = sqrtf(sq1) / (1.0f + sq1);
#pragma unroll
                for (int o = 0; o < 8; ++o) v_r[bb][o] = fmaf(val1[o], sc1, v_r[bb][o]);
            }
        }
    }

    {
        const int xb   = t >> 4;
        const int xig  = t & 7;
        const int half = (t >> 3) & 1;
        const float* xp = X + (size_t)(b0 + xb) * (NI * ND) + (size_t)(i0 + xig) * ND + half * 8;
        float4 f0 = *(const float4*)(xp);
        float4 f1 = *(const float4*)(xp + 4);
        float vals[8] = {f0.x,f0.y,f0.z,f0.w,f1.x,f1.y,f1.z,f1.w};
        const int m = (xig & 7) << 3;
#pragma unroll
        for (int jj = 0; jj < 8; ++jj) {
            const int d = half * 8 + jj;
            Xs[xig * 256 + ((16 * d + xb) ^ m)] = vals[jj];
        }
    }

    for (int ii = 0; ii < IC; ++ii) {
        const int i = i0 + ii;
        __syncthreads();
        {
            const float4* wsrc = (const float4*)(Wg + (size_t)i * 8192);
#pragma unroll
            for (int j = 0; j < 8; ++j) {
                float4 val = wsrc[t + j * 256];
                const int k = (t >> 6) + 4 * j;
                ((float4*)Ws)[k * 64 + ((t & 63) ^ (k & 7))] = val;
            }
        }
        __syncthreads();

        const int xm = (ii & 7) << 3;
        float u[4][8];
        if constexpr (VMODE >= 1) {
#pragma unroll
            for (int bb = 0; bb < 4; ++bb)
#pragma unroll
                for (int o = 0; o < 8; ++o) u[bb][o] = 0.f;
        }
#pragma unroll
        for (int d = 0; d < 16; ++d) {
            const float4 x4 = *(const float4*)(&Xs[ii * 256 + ((16 * d + 4 * bq4) ^ xm)]);
            float wvv[8];
            {
                const float4 wA = ((const float4*)Ws)[kk * 64 + ((d * 4 + oh * 2)     ^ (kk & 7))];
                const float4 wB = ((const float4*)Ws)[kk * 64 + ((d * 4 + oh * 2 + 1) ^ (kk & 7))];
                wvv[0]=wA.x; wvv[1]=wA.y; wvv[2]=wA.z; wvv[3]=wA.w;
                wvv[4]=wB.x; wvv[5]=wB.y; wvv[6]=wB.z; wvv[7]=wB.w;
            }
            if constexpr (VMODE >= 1) {
#pragma unroll
                for (int o = 0; o < 8; ++o) {
                    u[0][o] = fmaf(x4.x, wvv[o], u[0][o]);
                    u[1][o] = fmaf(x4.y, wvv[o], u[1][o]);
                    u[2][o] = fmaf(x4.z, wvv[o], u[2][o]);
                    u[3][o] = fmaf(x4.w, wvv[o], u[3][o]);
                }
            } else {
#pragma unroll
                for (int o = 0; o < 8; ++o) {
                    s_acc[0][o] = fmaf(x4.x, wvv[o], s_acc[0][o]);
                    s_acc[1][o] = fmaf(x4.y, wvv[o], s_acc[1][o]);
                    s_acc[2][o] = fmaf(x4.z, wvv[o], s_acc[2][o]);
                    s_acc[3][o] = fmaf(x4.w, wvv[o], s_acc[3][o]);
                }
            }
        }

        if constexpr (VMODE >= 1) {
#pragma unroll
            for (int bb = 0; bb < 4; ++bb) {
                float lg = 0.f;
#pragma unroll
                for (int o = 0; o < 8; ++o) lg = fmaf(u[bb][o], v_r[bb][o], lg);
                lg += __shfl_xor(lg, 32);
                float m = lg;
#pragma unroll
                for (int mask = 16; mask >= 1; mask >>= 1)
                    m = fmaxf(m, __shfl_xor(m, mask));
                const float e = __expf(lg - m);
                float ssum = e;
#pragma unroll
                for (int mask = 16; mask >= 1; mask >>= 1)
                    ssum += __shfl_xor(ssum, mask);
                const float c = e / ssum;
#pragma unroll
                for (int o = 0; o < 8; ++o)
                    s_acc[bb][o] = fmaf(c, u[bb][o], s_acc[bb][o]);
            }
        }
    }

#pragma unroll
    for (int bb = 0; bb < 4; ++bb) {
        float* sp = Sout + ((size_t)(b0 + bq4 * 4 + bb) * NK + kk) * 16 + oh * 8;
#pragma unroll
        for (int o = 0; o < 8; ++o) atomicAdd(sp + o, s_acc[bb][o]);
    }
}

__global__ __launch_bounds__(256)
void squash_kernel(const float* __restrict__ S, float* __restrict__ Vout)
{
    const int idx = blockIdx.x * 256 + threadIdx.x;
    float val = S[idx];
    float sq = val * val;
#pragma unroll
    for (int mask = 8; mask >= 1; mask >>= 1) sq += __shfl_xor(sq, mask);
    const float sc = sqrtf(sq) / (1.0f + sq);
    Vout[idx] = val * sc;
}

extern "C" void kernel_launch(void* const* d_in, const int* in_sizes, int n_in,
                              void* d_out, int out_size, void* d_ws, size_t ws_size,
                              hipStream_t stream)
{
    const float* X  = (const float*)d_in[0];   // [64][2048][16]
    const float* Wg = (const float*)d_in[1];   // [2048][32][16][16]
    float* out = (float*)d_out;                // [64][32][16]

    const size_t WHU  = (size_t)2048 * 4096;        // u32
    const size_t XHU  = (size_t)64 * 2048 * 8;      // u32
    const size_t PART = (size_t)1024 * 8192;        // f32
    const size_t need = (WHU + XHU) * 4 + (PART + 3 * 32768) * 4;  // ~68.4 MB

    const dim3 blk(256), pgrid(1024), rgrid(512);

    if (ws_size >= need) {
        uint32_t* Wh = (uint32_t*)d_ws;
        uint32_t* Xh = Wh + WHU;
        float* part  = (float*)(Xh + XHU);
        float* s0    = part + PART;
        float* v0    = s0 + 32768;
        float* v01   = v0 + 32768;

        conv_w<<<dim3(2048), blk, 0, stream>>>(Wg, Wh);
        conv_x<<<dim3(1024), blk, 0, stream>>>(X, Xh);

        caps_pass_h<0><<<pgrid, blk, 0, stream>>>(Xh, Wh, nullptr, part);
        caps_reduce<0><<<rgrid, blk, 0, stream>>>(part, nullptr, s0, v0);
        caps_pass_h<1><<<pgrid, blk, 0, stream>>>(Xh, Wh, v0, part);
        caps_reduce<1><<<rgrid, blk, 0, stream>>>(part, s0, nullptr, v01);
        caps_pass_h<1><<<pgrid, blk, 0, stream>>>(Xh, Wh, v01, part);
        caps_reduce<2><<<rgrid, blk, 0, stream>>>(part, nullptr, nullptr, out);
    } else {
        // fallback: f32 atomic path
        float* s0 = (float*)d_ws;
        float* s1 = s0 + 32768;
        float* s2 = s1 + 32768;
        hipMemsetAsync(d_ws, 0, (size_t)3 * 32768 * sizeof(float), stream);
        caps_pass_f32<0><<<pgrid, blk, 0, stream>>>(X, Wg, nullptr, nullptr, s0);
        caps_pass_f32<1><<<pgrid, blk, 0, stream>>>(X, Wg, s0, nullptr, s1);
        caps_pass_f32<2><<<pgrid, blk, 0, stream>>>(X, Wg, s0, s1, s2);
        squash_kernel<<<dim3(128), blk, 0, stream>>>(s2, out);
    }
}

// Round 6
// 160.636 us; speedup vs baseline: 6.0919x; 1.1124x over previous
//
#include <hip/hip_runtime.h>
#include <math.h>
#include <stdint.h>

// Problem constants
#define NB 64       // batch
#define NI 2048     // input capsules
#define NK 32       // output capsules
#define ND 16       // in_dim = out_dim

typedef _Float16 h2t __attribute__((ext_vector_type(2)));

#if defined(__has_builtin)
#if __has_builtin(__builtin_amdgcn_fdot2)
#define USE_FDOT2 1
#endif
#if __has_builtin(__builtin_amdgcn_global_load_lds)
#define HAVE_GLL 1
#endif
#endif
#ifndef USE_FDOT2
#define USE_FDOT2 0
#endif
#ifndef HAVE_GLL
#define HAVE_GLL 0
#endif

static __device__ __forceinline__ float dot2acc(uint32_t w, uint32_t x, float c) {
#if USE_FDOT2
    return __builtin_amdgcn_fdot2(__builtin_bit_cast(h2t, w),
                                  __builtin_bit_cast(h2t, x), c, false);
#else
    h2t wh = __builtin_bit_cast(h2t, w);
    h2t xh = __builtin_bit_cast(h2t, x);
    return fmaf((float)wh.x, (float)xh.x, fmaf((float)wh.y, (float)xh.y, c));
#endif
}

static __device__ __forceinline__ uint32_t pack_h2(float a, float b) {
    h2t p; p.x = (_Float16)a; p.y = (_Float16)b;
    return __builtin_bit_cast(uint32_t, p);
}

// 16-lane row scan-sum via DPP row_ror (VALU pipe, not DS).
static __device__ __forceinline__ float dpp_row_sum16(float x) {
    int v;
    v = __builtin_amdgcn_update_dpp(0, __builtin_bit_cast(int, x), 0x121, 0xF, 0xF, true);
    x += __builtin_bit_cast(float, v);
    v = __builtin_amdgcn_update_dpp(0, __builtin_bit_cast(int, x), 0x122, 0xF, 0xF, true);
    x += __builtin_bit_cast(float, v);
    v = __builtin_amdgcn_update_dpp(0, __builtin_bit_cast(int, x), 0x124, 0xF, 0xF, true);
    x += __builtin_bit_cast(float, v);
    v = __builtin_amdgcn_update_dpp(0, __builtin_bit_cast(int, x), 0x128, 0xF, 0xF, true);
    x += __builtin_bit_cast(float, v);
    return x;
}
// exchange across 16-lane rows within each 32-lane half (xor 16)
static __device__ __forceinline__ float swz_xor16(float x) {
    int v = __builtin_amdgcn_ds_swizzle(__builtin_bit_cast(int, x), 0x401F);
    return __builtin_bit_cast(float, v);
}

// ---------------------------------------------------------------------------
// Convert W f32 [2048][32][16][16] -> f16 d-pair-packed, PRE-SWIZZLED tiles.
// Coalesced global read via padded-LDS round trip.
// ---------------------------------------------------------------------------
__global__ __launch_bounds__(256)
void conv_w(const float* __restrict__ Wg, uint32_t* __restrict__ Wh)
{
    __shared__ float tile[32 * 264];    // k-stride 264 breaks bank alignment
    const int i = blockIdx.x;           // 0..2047
    const int t = threadIdx.x;
    const float4* src = (const float4*)(Wg + (size_t)i * 8192);
#pragma unroll
    for (int j = 0; j < 8; ++j) {
        const int f4 = t + j * 256;          // float4 index 0..2047
        const int k  = f4 >> 6;              // 64 float4 per k-block
        const int r4 = f4 & 63;
        *(float4*)(&tile[k * 264 + r4 * 4]) = src[f4];
    }
    __syncthreads();
    const int k   = t >> 3;            // 0..31
    const int sub = t & 7;             // 0..7
    const float* s = tile + k * 264;
    uint4* dst4 = (uint4*)(Wh + (size_t)i * 4096 + k * 128);
#pragma unroll
    for (int uu = 0; uu < 4; ++uu) {
        const int u   = sub * 4 + uu;  // 0..31
        const int o   = u >> 1;
        const int dph = u & 1;
        uint32_t out[4];
#pragma unroll
        for (int pos = 0; pos < 4; ++pos) {
            const int dp = dph * 4 + pos;
            const float a = s[(2 * dp) * 16 + o];
            const float b = s[(2 * dp + 1) * 16 + o];
            out[pos] = pack_h2(a, b);
        }
        uint4 v; v.x = out[0]; v.y = out[1]; v.z = out[2]; v.w = out[3];
        dst4[u ^ k] = v;
    }
}

// ---------------------------------------------------------------------------
// Convert X f32 -> f16 d-pair-packed.
// ---------------------------------------------------------------------------
__global__ __launch_bounds__(256)
void conv_x(const float* __restrict__ X, uint32_t* __restrict__ Xh)
{
    const size_t idx = (size_t)blockIdx.x * 256 + threadIdx.x;   // 0..262143
    const float4 f0 = ((const float4*)X)[idx * 2];
    const float4 f1 = ((const float4*)X)[idx * 2 + 1];
    uint4 v;
    v.x = pack_h2(f0.x, f0.y);
    v.y = pack_h2(f0.z, f0.w);
    v.z = pack_h2(f1.x, f1.y);
    v.w = pack_h2(f1.z, f1.w);
    ((uint4*)Xh)[idx] = v;
}

// ---------------------------------------------------------------------------
// f16 fused routing pass (double-buffered W staging via global_load_lds).
// VMODE=0: s[b,k,o] = sum_i sum_d x*W (uniform c folded as /32 in reduce)
// VMODE=1: u=u_hat; lg=<u,V[b,k,:]>; c=softmax_k(lg) (no max-sub; |lg| small);
//          s += c*u.  Partials: part[slab][16b][32k][16o], slab=bg*256+ichunk.
// Thread map: kk=t&31, oh=(t>>5)&1, bq4=t>>6. Block = 16 b x 8 i.
// ---------------------------------------------------------------------------
template<int VMODE>
__global__ __launch_bounds__(256, 4)
void caps_pass_h(const uint32_t* __restrict__ Xh,   // [64][2048][8] u32
                 const uint32_t* __restrict__ Wh,   // [2048][4096] u32 tiles
                 const float* __restrict__ V,       // [64][32][16] (VMODE=1)
                 float* __restrict__ part)
{
    constexpr int IC = 8;
    __shared__ uint32_t Ws[2][4096];   // 2 x 16 KB W tiles
    __shared__ uint32_t Xs[1024];      // [ig][dp][16b] 4 KB

    const int t   = threadIdx.x;
    const int kk  = t & 31;
    const int oh  = (t >> 5) & 1;
    const int bq4 = t >> 6;

    const int wg     = blockIdx.x;
    const int xcd    = wg & 7;
    const int slot   = wg >> 3;
    const int ichunk = xcd * 32 + (slot >> 2);   // 0..255
    const int bg     = slot & 3;
    const int i0 = ichunk * IC;
    const int b0 = bg * 16;

    float s_acc[4][8];
#pragma unroll
    for (int bb = 0; bb < 4; ++bb)
#pragma unroll
        for (int oo = 0; oo < 8; ++oo) s_acc[bb][oo] = 0.f;

    float v_r[4][8];
    if constexpr (VMODE == 1) {
#pragma unroll
        for (int bb = 0; bb < 4; ++bb) {
            const float* vp = V + ((size_t)(b0 + bq4 * 4 + bb) * NK + kk) * 16 + oh * 8;
            float4 a = *(const float4*)(vp);
            float4 c = *(const float4*)(vp + 4);
            v_r[bb][0]=a.x; v_r[bb][1]=a.y; v_r[bb][2]=a.z; v_r[bb][3]=a.w;
            v_r[bb][4]=c.x; v_r[bb][5]=c.y; v_r[bb][6]=c.z; v_r[bb][7]=c.w;
        }
    }

    // ---- stage X chunk: Xs[ig][dp][b] ----
    {
        const int xb  = t >> 4;        // 0..15
        const int ig  = (t >> 1) & 7;  // 0..7
        const int dph = t & 1;
        uint4 v = *(const uint4*)(Xh + (size_t)(b0 + xb) * 16384 + (size_t)(i0 + ig) * 8 + dph * 4);
        const int base = ig * 128 + dph * 64 + xb;   // + q*16 for dp=dph*4+q
        Xs[base]      = v.x;
        Xs[base + 16] = v.y;
        Xs[base + 32] = v.z;
        Xs[base + 48] = v.w;
    }

    // ---- prologue: stage W[i0] into buf 0 ----
    const int l  = t & 63;
    const int wv = t >> 6;
#if HAVE_GLL
#pragma unroll
    for (int j = 0; j < 4; ++j) {
        const int p = wv * 4 + j;
        const uint32_t* g = Wh + (size_t)i0 * 4096 + p * 256 + l * 4;
        __builtin_amdgcn_global_load_lds(
            (const __attribute__((address_space(1))) void*)g,
            (__attribute__((address_space(3))) void*)&Ws[0][p * 256], 16, 0, 0);
    }
#else
#pragma unroll
    for (int j = 0; j < 4; ++j) {
        const int p = wv * 4 + j;
        ((uint4*)&Ws[0][p * 256])[l] = *(const uint4*)(Wh + (size_t)i0 * 4096 + p * 256 + l * 4);
    }
#endif

    for (int ii = 0; ii < IC; ++ii) {
        __syncthreads();   // drains staged W for buf[ii&1]; protects prev readers

        // ---- issue next-tile stage into the other buffer (overlaps compute) ----
        if (ii + 1 < IC) {
            const int nxt = (ii + 1) & 1;
            const size_t ibase = (size_t)(i0 + ii + 1) * 4096;
#if HAVE_GLL
#pragma unroll
            for (int j = 0; j < 4; ++j) {
                const int p = wv * 4 + j;
                const uint32_t* g = Wh + ibase + p * 256 + l * 4;
                __builtin_amdgcn_global_load_lds(
                    (const __attribute__((address_space(1))) void*)g,
                    (__attribute__((address_space(3))) void*)&Ws[nxt][p * 256], 16, 0, 0);
            }
#else
#pragma unroll
            for (int j = 0; j < 4; ++j) {
                const int p = wv * 4 + j;
                ((uint4*)&Ws[nxt][p * 256])[l] = *(const uint4*)(Wh + ibase + p * 256 + l * 4);
            }
#endif
        }

        // ---- compute u_hat via packed f16 dot2 ----
        const uint4* W4 = (const uint4*)Ws[ii & 1];
        const uint4* X4 = (const uint4*)Xs;

        float u[4][8];
        if constexpr (VMODE == 1) {
#pragma unroll
            for (int bb = 0; bb < 4; ++bb)
#pragma unroll
                for (int oo = 0; oo < 8; ++oo) u[bb][oo] = 0.f;
        }

#pragma unroll
        for (int dph = 0; dph < 2; ++dph) {
            const uint4 xq0 = X4[ii * 32 + (dph * 4 + 0) * 4 + bq4];
            const uint4 xq1 = X4[ii * 32 + (dph * 4 + 1) * 4 + bq4];
            const uint4 xq2 = X4[ii * 32 + (dph * 4 + 2) * 4 + bq4];
            const uint4 xq3 = X4[ii * 32 + (dph * 4 + 3) * 4 + bq4];
#pragma unroll
            for (int oo = 0; oo < 8; ++oo) {
                const int un = (((oh * 8 + oo) * 2 + dph) ^ kk);
                const uint4 w4 = W4[kk * 32 + un];
#define DOT_Q(TGT, WQ, XQ) \
                TGT[0][oo] = dot2acc(WQ, XQ.x, TGT[0][oo]); \
                TGT[1][oo] = dot2acc(WQ, XQ.y, TGT[1][oo]); \
                TGT[2][oo] = dot2acc(WQ, XQ.z, TGT[2][oo]); \
                TGT[3][oo] = dot2acc(WQ, XQ.w, TGT[3][oo]);
                if constexpr (VMODE == 0) {
                    // pass A: accumulate straight into s_acc (no u, no extra add)
                    DOT_Q(s_acc, w4.x, xq0)
                    DOT_Q(s_acc, w4.y, xq1)
                    DOT_Q(s_acc, w4.z, xq2)
                    DOT_Q(s_acc, w4.w, xq3)
                } else {
                    DOT_Q(u, w4.x, xq0)
                    DOT_Q(u, w4.y, xq1)
                    DOT_Q(u, w4.z, xq2)
                    DOT_Q(u, w4.w, xq3)
                }
#undef DOT_Q
            }
        }

        if constexpr (VMODE == 1) {
#pragma unroll
            for (int bb = 0; bb < 4; ++bb) {
                float lg = 0.f;
#pragma unroll
                for (int oo = 0; oo < 8; ++oo) lg = fmaf(u[bb][oo], v_r[bb][oo], lg);
                lg += __shfl_xor(lg, 32);            // other o-half (1 DS op)
                // |lg| = |<u,v>| small: exp-safe without max-sub
                const float e = __expf(lg);
                // sum of e over the 32-lane k-group: 4 DPP adds + 1 swizzle
                float ssum = dpp_row_sum16(e);
                ssum += swz_xor16(ssum);
                const float c = e * __builtin_amdgcn_rcpf(ssum);
#pragma unroll
                for (int oo = 0; oo < 8; ++oo)
                    s_acc[bb][oo] = fmaf(c, u[bb][oo], s_acc[bb][oo]);
            }
        }
    }

    // ---- contiguous per-block partial tile ----
    const int slab = bg * 256 + ichunk;
    float4* p4 = (float4*)(part + (size_t)slab * 8192);
#pragma unroll
    for (int bb = 0; bb < 4; ++bb) {
        const int off = ((bq4 * 4 + bb) * 512 + kk * 16 + oh * 8) >> 2;
        float4 st0 = {s_acc[bb][0], s_acc[bb][1], s_acc[bb][2], s_acc[bb][3]};
        float4 st1 = {s_acc[bb][4], s_acc[bb][5], s_acc[bb][6], s_acc[bb][7]};
        p4[off]     = st0;
        p4[off + 1] = st1;
    }
}

// ---------------------------------------------------------------------------
// Reduce 256 partial slabs per output element + fused squash / v production.
// RMODE=0: s0 = sum; store s0; v0 = squash(s0/32)
// RMODE=1: v01 = squash(S0red/32) + squash(sum)
// RMODE=2: out = squash(sum)
// ---------------------------------------------------------------------------
template<int RMODE>
__global__ __launch_bounds__(256)
void caps_reduce(const float* __restrict__ part,
                 const float* __restrict__ S0red,
                 float* __restrict__ S0out,
                 float* __restrict__ Vout)
{
    __shared__ float red[4][64];
    const int t   = threadIdx.x;
    const int jl  = t & 63;
    const int qc  = t >> 6;
    const int jb  = blockIdx.x * 64;
    const int j   = jb + jl;
    const int bg  = j >> 13;
    const int loc = j & 8191;
    const float* p = part + ((size_t)(bg * 256 + qc * 64)) * 8192 + loc;
    float sum = 0.f;
#pragma unroll 8
    for (int ic = 0; ic < 64; ++ic) sum += p[(size_t)ic * 8192];
    red[qc][jl] = sum;
    __syncthreads();
    if (t < 64) {
        const int jj = jb + t;
        float total = red[0][t] + red[1][t] + red[2][t] + red[3][t];
        if constexpr (RMODE == 0) {
            S0out[jj] = total;
            float val = total * (1.0f / 32.0f);
            float sq = val * val;
#pragma unroll
            for (int mask = 8; mask >= 1; mask >>= 1) sq += __shfl_xor(sq, mask);
            const float sc = sqrtf(sq) / (1.0f + sq);
            Vout[jj] = val * sc;
        } else if constexpr (RMODE == 1) {
            float val0 = S0red[jj] * (1.0f / 32.0f);
            float sq0 = val0 * val0;
#pragma unroll
            for (int mask = 8; mask >= 1; mask >>= 1) sq0 += __shfl_xor(sq0, mask);
            const float sc0 = sqrtf(sq0) / (1.0f + sq0);
            float sq1 = total * total;
#pragma unroll
            for (int mask = 8; mask >= 1; mask >>= 1) sq1 += __shfl_xor(sq1, mask);
            const float sc1 = sqrtf(sq1) / (1.0f + sq1);
            Vout[jj] = fmaf(val0, sc0, total * sc1);
        } else {
            float sq = total * total;
#pragma unroll
            for (int mask = 8; mask >= 1; mask >>= 1) sq += __shfl_xor(sq, mask);
            const float sc = sqrtf(sq) / (1.0f + sq);
            Vout[jj] = total * sc;
        }
    }
}

// ===========================================================================
// Fallback (small ws): proven R1-style f32 atomic path.
// ===========================================================================
template<int VMODE>
__global__ __launch_bounds__(256, 4)
void caps_pass_f32(const float* __restrict__ X,
                   const float* __restrict__ Wg,
                   const float* __restrict__ S0,
                   const float* __restrict__ S1,
                   float* __restrict__ Sout)
{
    constexpr int IC = 8;
    __shared__ float Ws[8192];
    __shared__ float Xs[2048];

    const int t   = threadIdx.x;
    const int kk  = t & 31;
    const int oh  = (t >> 5) & 1;
    const int bq4 = t >> 6;

    const int wg     = blockIdx.x;
    const int xcd    = wg & 7;
    const int slot   = wg >> 3;
    const int ichunk = xcd * 32 + (slot >> 2);
    const int bg     = slot & 3;
    const int i0 = ichunk * IC;
    const int b0 = bg * 16;

    float s_acc[4][8];
#pragma unroll
    for (int bb = 0; bb < 4; ++bb)
#pragma unroll
        for (int o = 0; o < 8; ++o) s_acc[bb][o] = 0.f;

    float v_r[4][8];
    if constexpr (VMODE >= 1) {
#pragma unroll
        for (int bb = 0; bb < 4; ++bb) {
            const int b = b0 + bq4 * 4 + bb;
            const float* p0 = S0 + ((size_t)b * NK + kk) * 16 + oh * 8;
            float4 a = *(const float4*)(p0);
            float4 c = *(const float4*)(p0 + 4);
            float val0[8] = {a.x,a.y,a.z,a.w,c.x,c.y,c.z,c.w};
            float sq0 = 0.f;
#pragma unroll
            for (int o = 0; o < 8; ++o) { val0[o] *= (1.0f/32.0f); sq0 = fmaf(val0[o], val0[o], sq0); }
            sq0 += __shfl_xor(sq0, 32);
            const float sc0 = sqrtf(sq0) / (1.0f + sq0);
#pragma unroll
            for (int o = 0; o < 8; ++o) v_r[bb][o] = val0[o] * sc0;
            if constexpr (VMODE == 2) {
                const float* p1 = S1 + ((size_t)b * NK + kk) * 16 + oh * 8;
                float4 a1 = *(const float4*)(p1);
                float4 c1 = *(const float4*)(p1 + 4);
                float val1[8] = {a1.x,a1.y,a1.z,a1.w,c1.x,c1.y,c1.z,c1.w};
                float sq1 = 0.f;
#pragma unroll
                for (int o = 0; o < 8; ++o) sq1 = fmaf(val1[o], val1[o], sq1);
                sq1 += __shfl_xor(sq1, 32);
                const float sc1 = sqrtf(sq1) / (1.0f + sq1);
#pragma unroll
                for (int o = 0; o < 8; ++o) v_r[bb][o] = fmaf(val1[o], sc1, v_r[bb][o]);
            }
        }
    }

    {
        const int xb   = t >> 4;
        const int xig  = t & 7;
        const int half = (t >> 3) & 1;
        const float* xp = X + (size_t)(b0 + xb) * (NI * ND) + (size_t)(i0 + xig) * ND + half * 8;
        float4 f0 = *(const float4*)(xp);
        float4 f1 = *(const float4*)(xp + 4);
        float vals[8] = {f0.x,f0.y,f0.z,f0.w,f1.x,f1.y,f1.z,f1.w};
        const int m = (xig & 7) << 3;
#pragma unroll
        for (int jj = 0; jj < 8; ++jj) {
            const int d = half * 8 + jj;
            Xs[xig * 256 + ((16 * d + xb) ^ m)] = vals[jj];
        }
    }

    for (int ii = 0; ii < IC; ++ii) {
        const int i = i0 + ii;
        __syncthreads();
        {
            const float4* wsrc = (const float4*)(Wg + (size_t)i * 8192);
#pragma unroll
            for (int j = 0; j < 8; ++j) {
                float4 val = wsrc[t + j * 256];
                const int k = (t >> 6) + 4 * j;
                ((float4*)Ws)[k * 64 + ((t & 63) ^ (k & 7))] = val;
            }
        }
        __syncthreads();

        const int xm = (ii & 7) << 3;
        float u[4][8];
        if constexpr (VMODE >= 1) {
#pragma unroll
            for (int bb = 0; bb < 4; ++bb)
#pragma unroll
                for (int o = 0; o < 8; ++o) u[bb][o] = 0.f;
        }
#pragma unroll
        for (int d = 0; d < 16; ++d) {
            const float4 x4 = *(const float4*)(&Xs[ii * 256 + ((16 * d + 4 * bq4) ^ xm)]);
            float wvv[8];
            {
                const float4 wA = ((const float4*)Ws)[kk * 64 + ((d * 4 + oh * 2)     ^ (kk & 7))];
                const float4 wB = ((const float4*)Ws)[kk * 64 + ((d * 4 + oh * 2 + 1) ^ (kk & 7))];
                wvv[0]=wA.x; wvv[1]=wA.y; wvv[2]=wA.z; wvv[3]=wA.w;
                wvv[4]=wB.x; wvv[5]=wB.y; wvv[6]=wB.z; wvv[7]=wB.w;
            }
            if constexpr (VMODE >= 1) {
#pragma unroll
                for (int o = 0; o < 8; ++o) {
                    u[0][o] = fmaf(x4.x, wvv[o], u[0][o]);
                    u[1][o] = fmaf(x4.y, wvv[o], u[1][o]);
                    u[2][o] = fmaf(x4.z, wvv[o], u[2][o]);
                    u[3][o] = fmaf(x4.w, wvv[o], u[3][o]);
                }
            } else {
#pragma unroll
                for (int o = 0; o < 8; ++o) {
                    s_acc[0][o] = fmaf(x4.x, wvv[o], s_acc[0][o]);
                    s_acc[1][o] = fmaf(x4.y, wvv[o], s_acc[1][o]);
                    s_acc[2][o] = fmaf(x4.z, wvv[o], s_acc[2][o]);
                    s_acc[3][o] = fmaf(x4.w, wvv[o], s_acc[3][o]);
                }
            }
        }

        if constexpr (VMODE >= 1) {
#pragma unroll
            for (int bb = 0; bb < 4; ++bb) {
                float lg = 0.f;
#pragma unroll
                for (int o = 0; o < 8; ++o) lg = fmaf(u[bb][o], v_r[bb][o], lg);
                lg += __shfl_xor(lg, 32);
                float m = lg;
#pragma unroll
                for (int mask = 16; mask >= 1; mask >>= 1)
                    m = fmaxf(m, __shfl_xor(m, mask));
                const float e = __expf(lg - m);
                float ssum = e;
#pragma unroll
                for (int mask = 16; mask >= 1; mask >>= 1)
                    ssum += __shfl_xor(ssum, mask);
                const float c = e / ssum;
#pragma unroll
                for (int o = 0; o < 8; ++o)
                    s_acc[bb][o] = fmaf(c, u[bb][o], s_acc[bb][o]);
            }
        }
    }

#pragma unroll
    for (int bb = 0; bb < 4; ++bb) {
        float* sp = Sout + ((size_t)(b0 + bq4 * 4 + bb) * NK + kk) * 16 + oh * 8;
#pragma unroll
        for (int o = 0; o < 8; ++o) atomicAdd(sp + o, s_acc[bb][o]);
    }
}

__global__ __launch_bounds__(256)
void squash_kernel(const float* __restrict__ S, float* __restrict__ Vout)
{
    const int idx = blockIdx.x * 256 + threadIdx.x;
    float val = S[idx];
    float sq = val * val;
#pragma unroll
    for (int mask = 8; mask >= 1; mask >>= 1) sq += __shfl_xor(sq, mask);
    const float sc = sqrtf(sq) / (1.0f + sq);
    Vout[idx] = val * sc;
}

extern "C" void kernel_launch(void* const* d_in, const int* in_sizes, int n_in,
                              void* d_out, int out_size, void* d_ws, size_t ws_size,
                              hipStream_t stream)
{
    const float* X  = (const float*)d_in[0];   // [64][2048][16]
    const float* Wg = (const float*)d_in[1];   // [2048][32][16][16]
    float* out = (float*)d_out;                // [64][32][16]

    const size_t WHU  = (size_t)2048 * 4096;        // u32
    const size_t XHU  = (size_t)64 * 2048 * 8;      // u32
    const size_t PART = (size_t)1024 * 8192;        // f32
    const size_t need = (WHU + XHU) * 4 + (PART + 3 * 32768) * 4;  // ~68.4 MB

    const dim3 blk(256), pgrid(1024), rgrid(512);

    if (ws_size >= need) {
        uint32_t* Wh = (uint32_t*)d_ws;
        uint32_t* Xh = Wh + WHU;
        float* part  = (float*)(Xh + XHU);
        float* s0    = part + PART;
        float* v0    = s0 + 32768;
        float* v01   = v0 + 32768;

        conv_w<<<dim3(2048), blk, 0, stream>>>(Wg, Wh);
        conv_x<<<dim3(1024), blk, 0, stream>>>(X, Xh);

        caps_pass_h<0><<<pgrid, blk, 0, stream>>>(Xh, Wh, nullptr, part);
        caps_reduce<0><<<rgrid, blk, 0, stream>>>(part, nullptr, s0, v0);
        caps_pass_h<1><<<pgrid, blk, 0, stream>>>(Xh, Wh, v0, part);
        caps_reduce<1><<<rgrid, blk, 0, stream>>>(part, s0, nullptr, v01);
        caps_pass_h<1><<<pgrid, blk, 0, stream>>>(Xh, Wh, v01, part);
        caps_reduce<2><<<rgrid, blk, 0, stream>>>(part, nullptr, nullptr, out);
    } else {
        // fallback: f32 atomic path
        float* s0 = (float*)d_ws;
        float* s1 = s0 + 32768;
        float* s2 = s1 + 32768;
        hipMemsetAsync(d_ws, 0, (size_t)3 * 32768 * sizeof(float), stream);
        caps_pass_f32<0><<<pgrid, blk, 0, stream>>>(X, Wg, nullptr, nullptr, s0);
        caps_pass_f32<1><<<pgrid, blk, 0, stream>>>(X, Wg, s0, nullptr, s1);
        caps_pass_f32<2><<<pgrid, blk, 0, stream>>>(X, Wg, s0, s1, s2);
        squash_kernel<<<dim3(128), blk, 0, stream>>>(s2, out);
    }
}

// Round 7
// 148.061 us; speedup vs baseline: 6.6093x; 1.0849x over previous
//
#include <hip/hip_runtime.h>
#include <math.h>
#include <stdint.h>

// Problem constants
#define NB 64       // batch
#define NI 2048     // input capsules
#define NK 32       // output capsules
#define ND 16       // in_dim = out_dim

typedef _Float16 h2t __attribute__((ext_vector_type(2)));

#if defined(__has_builtin)
#if __has_builtin(__builtin_amdgcn_fdot2)
#define USE_FDOT2 1
#endif
#if __has_builtin(__builtin_amdgcn_global_load_lds)
#define HAVE_GLL 1
#endif
#endif
#ifndef USE_FDOT2
#define USE_FDOT2 0
#endif
#ifndef HAVE_GLL
#define HAVE_GLL 0
#endif

static __device__ __forceinline__ float dot2acc(uint32_t w, uint32_t x, float c) {
#if USE_FDOT2
    return __builtin_amdgcn_fdot2(__builtin_bit_cast(h2t, w),
                                  __builtin_bit_cast(h2t, x), c, false);
#else
    h2t wh = __builtin_bit_cast(h2t, w);
    h2t xh = __builtin_bit_cast(h2t, x);
    return fmaf((float)wh.x, (float)xh.x, fmaf((float)wh.y, (float)xh.y, c));
#endif
}

static __device__ __forceinline__ uint32_t pack_h2(float a, float b) {
    h2t p; p.x = (_Float16)a; p.y = (_Float16)b;
    return __builtin_bit_cast(uint32_t, p);
}

// 16-lane row all-sum via DPP row_ror (VALU pipe, not DS).
static __device__ __forceinline__ float dpp_row_sum16(float x) {
    int v;
    v = __builtin_amdgcn_update_dpp(0, __builtin_bit_cast(int, x), 0x121, 0xF, 0xF, true);
    x += __builtin_bit_cast(float, v);
    v = __builtin_amdgcn_update_dpp(0, __builtin_bit_cast(int, x), 0x122, 0xF, 0xF, true);
    x += __builtin_bit_cast(float, v);
    v = __builtin_amdgcn_update_dpp(0, __builtin_bit_cast(int, x), 0x124, 0xF, 0xF, true);
    x += __builtin_bit_cast(float, v);
    v = __builtin_amdgcn_update_dpp(0, __builtin_bit_cast(int, x), 0x128, 0xF, 0xF, true);
    x += __builtin_bit_cast(float, v);
    return x;
}
// exchange across 16-lane rows within each 32-lane half (xor 16)
static __device__ __forceinline__ float swz_xor16(float x) {
    int v = __builtin_amdgcn_ds_swizzle(__builtin_bit_cast(int, x), 0x401F);
    return __builtin_bit_cast(float, v);
}

// ---------------------------------------------------------------------------
// Convert W f32 [2048][32][16][16] -> f16 d-pair-packed, PRE-SWIZZLED tiles.
// ---------------------------------------------------------------------------
__global__ __launch_bounds__(256)
void conv_w(const float* __restrict__ Wg, uint32_t* __restrict__ Wh)
{
    __shared__ float tile[32 * 264];
    const int i = blockIdx.x;           // 0..2047
    const int t = threadIdx.x;
    const float4* src = (const float4*)(Wg + (size_t)i * 8192);
#pragma unroll
    for (int j = 0; j < 8; ++j) {
        const int f4 = t + j * 256;
        const int k  = f4 >> 6;
        const int r4 = f4 & 63;
        *(float4*)(&tile[k * 264 + r4 * 4]) = src[f4];
    }
    __syncthreads();
    const int k   = t >> 3;
    const int sub = t & 7;
    const float* s = tile + k * 264;
    uint4* dst4 = (uint4*)(Wh + (size_t)i * 4096 + k * 128);
#pragma unroll
    for (int uu = 0; uu < 4; ++uu) {
        const int u   = sub * 4 + uu;
        const int o   = u >> 1;
        const int dph = u & 1;
        uint32_t out[4];
#pragma unroll
        for (int pos = 0; pos < 4; ++pos) {
            const int dp = dph * 4 + pos;
            const float a = s[(2 * dp) * 16 + o];
            const float b = s[(2 * dp + 1) * 16 + o];
            out[pos] = pack_h2(a, b);
        }
        uint4 v; v.x = out[0]; v.y = out[1]; v.z = out[2]; v.w = out[3];
        dst4[u ^ k] = v;
    }
}

// ---------------------------------------------------------------------------
// Convert X f32 -> f16 d-pair-packed.
// ---------------------------------------------------------------------------
__global__ __launch_bounds__(256)
void conv_x(const float* __restrict__ X, uint32_t* __restrict__ Xh)
{
    const size_t idx = (size_t)blockIdx.x * 256 + threadIdx.x;
    const float4 f0 = ((const float4*)X)[idx * 2];
    const float4 f1 = ((const float4*)X)[idx * 2 + 1];
    uint4 v;
    v.x = pack_h2(f0.x, f0.y);
    v.y = pack_h2(f0.z, f0.w);
    v.z = pack_h2(f1.x, f1.y);
    v.w = pack_h2(f1.z, f1.w);
    ((uint4*)Xh)[idx] = v;
}

// ---------------------------------------------------------------------------
// f16 fused routing pass — 3-deep W ring, counted vmcnt + raw barrier.
// VMODE=0: s[b,k,o] = sum_i sum_d x*W (uniform c folded as /32 in reduce)
// VMODE=1: u=u_hat; lg=<u,V>; c=softmax_k(lg); s += c*u.
// Thread map: kk=t&31, oh=(t>>5)&1, bq4=t>>6. Block = 16 b x 8 i.
// Pipeline per iter ii: [wait vmcnt(4): tile ii landed] [s_barrier]
//   [issue tile ii+2 into ring buf] [compute tile ii].
// Issue-after-barrier guarantees no wave still reads the buf being overwritten
// (it held tile ii-1, whose readers are all past this barrier).
// ---------------------------------------------------------------------------
template<int VMODE>
__global__ __launch_bounds__(256, 3)
void caps_pass_h(const uint32_t* __restrict__ Xh,   // [64][2048][8] u32
                 const uint32_t* __restrict__ Wh,   // [2048][4096] u32 tiles
                 const float* __restrict__ V,       // [64][32][16] (VMODE=1)
                 float* __restrict__ part)
{
    constexpr int IC = 8;
    __shared__ uint32_t Ws[3][4096];   // 3 x 16 KB W ring
    __shared__ uint32_t Xs[1024];      // [ig][dp][16b] 4 KB

    const int t   = threadIdx.x;
    const int kk  = t & 31;
    const int oh  = (t >> 5) & 1;
    const int bq4 = t >> 6;

    const int wg     = blockIdx.x;
    const int xcd    = wg & 7;
    const int slot   = wg >> 3;
    const int ichunk = xcd * 32 + (slot >> 2);   // 0..255
    const int bg     = slot & 3;
    const int i0 = ichunk * IC;
    const int b0 = bg * 16;

    float s_acc[4][8];
#pragma unroll
    for (int bb = 0; bb < 4; ++bb)
#pragma unroll
        for (int oo = 0; oo < 8; ++oo) s_acc[bb][oo] = 0.f;

    float v_r[4][8];
    if constexpr (VMODE == 1) {
#pragma unroll
        for (int bb = 0; bb < 4; ++bb) {
            const float* vp = V + ((size_t)(b0 + bq4 * 4 + bb) * NK + kk) * 16 + oh * 8;
            float4 a = *(const float4*)(vp);
            float4 c = *(const float4*)(vp + 4);
            v_r[bb][0]=a.x; v_r[bb][1]=a.y; v_r[bb][2]=a.z; v_r[bb][3]=a.w;
            v_r[bb][4]=c.x; v_r[bb][5]=c.y; v_r[bb][6]=c.z; v_r[bb][7]=c.w;
        }
    }

    // ---- stage X chunk: Xs[ig][dp][b] ----
    {
        const int xb  = t >> 4;        // 0..15
        const int ig  = (t >> 1) & 7;  // 0..7
        const int dph = t & 1;
        uint4 v = *(const uint4*)(Xh + (size_t)(b0 + xb) * 16384 + (size_t)(i0 + ig) * 8 + dph * 4);
        const int base = ig * 128 + dph * 64 + xb;
        Xs[base]      = v.x;
        Xs[base + 16] = v.y;
        Xs[base + 32] = v.z;
        Xs[base + 48] = v.w;
    }

    const int l  = t & 63;
    const int wv = t >> 6;

    // stage W[tile] into ring buffer `buf` (4 global_load_lds / thread)
#define STAGE_W(buf, tile)                                                     \
    {                                                                          \
        const size_t ibase_ = (size_t)(tile) * 4096;                           \
        _Pragma("unroll")                                                      \
        for (int j = 0; j < 4; ++j) {                                          \
            const int p = wv * 4 + j;                                          \
            STAGE_ONE(buf, ibase_, p)                                          \
        }                                                                      \
    }
#if HAVE_GLL
#define STAGE_ONE(buf, ibase_, p)                                              \
    __builtin_amdgcn_global_load_lds(                                          \
        (const __attribute__((address_space(1))) void*)(Wh + ibase_ + (p) * 256 + l * 4), \
        (__attribute__((address_space(3))) void*)&Ws[buf][(p) * 256], 16, 0, 0);
#define WAIT_PIPE(n) asm volatile("s_waitcnt vmcnt(" #n ")" ::: "memory");
#else
#define STAGE_ONE(buf, ibase_, p)                                              \
    ((uint4*)&Ws[buf][(p) * 256])[l] = *(const uint4*)(Wh + ibase_ + (p) * 256 + l * 4);
#define WAIT_PIPE(n) asm volatile("s_waitcnt vmcnt(0) lgkmcnt(0)" ::: "memory");
#endif

    // X visible to all waves before compute; also a clean vmcnt=0 point.
    __syncthreads();

    // prologue: issue tiles i0, i0+1
    STAGE_W(0, i0)
    STAGE_W(1, i0 + 1)

    int cur = 0;           // ring slot holding tile ii
    for (int ii = 0; ii < IC; ++ii) {
        // gate: tile ii landed (own loads), then all waves' loads landed
        if (ii + 1 < IC) { WAIT_PIPE(4) } else { WAIT_PIPE(0) }
        __builtin_amdgcn_s_barrier();

        // issue tile ii+2 into the slot that held tile ii-1 (readers done)
        if (ii + 2 < IC) {
            const int nslot = (cur + 2 >= 3) ? cur - 1 : cur + 2;
            STAGE_W(nslot, i0 + ii + 2)
        }

        // ---- compute u_hat via packed f16 dot2 ----
        const uint4* W4 = (const uint4*)Ws[cur];
        const uint4* X4 = (const uint4*)Xs;

        float u[4][8];
        if constexpr (VMODE == 1) {
#pragma unroll
            for (int bb = 0; bb < 4; ++bb)
#pragma unroll
                for (int oo = 0; oo < 8; ++oo) u[bb][oo] = 0.f;
        }

#pragma unroll
        for (int dph = 0; dph < 2; ++dph) {
            const uint4 xq0 = X4[ii * 32 + (dph * 4 + 0) * 4 + bq4];
            const uint4 xq1 = X4[ii * 32 + (dph * 4 + 1) * 4 + bq4];
            const uint4 xq2 = X4[ii * 32 + (dph * 4 + 2) * 4 + bq4];
            const uint4 xq3 = X4[ii * 32 + (dph * 4 + 3) * 4 + bq4];
#pragma unroll
            for (int oo = 0; oo < 8; ++oo) {
                const int un = (((oh * 8 + oo) * 2 + dph) ^ kk);
                const uint4 w4 = W4[kk * 32 + un];
#define DOT_Q(TGT, WQ, XQ) \
                TGT[0][oo] = dot2acc(WQ, XQ.x, TGT[0][oo]); \
                TGT[1][oo] = dot2acc(WQ, XQ.y, TGT[1][oo]); \
                TGT[2][oo] = dot2acc(WQ, XQ.z, TGT[2][oo]); \
                TGT[3][oo] = dot2acc(WQ, XQ.w, TGT[3][oo]);
                if constexpr (VMODE == 0) {
                    DOT_Q(s_acc, w4.x, xq0)
                    DOT_Q(s_acc, w4.y, xq1)
                    DOT_Q(s_acc, w4.z, xq2)
                    DOT_Q(s_acc, w4.w, xq3)
                } else {
                    DOT_Q(u, w4.x, xq0)
                    DOT_Q(u, w4.y, xq1)
                    DOT_Q(u, w4.z, xq2)
                    DOT_Q(u, w4.w, xq3)
                }
#undef DOT_Q
            }
        }

        if constexpr (VMODE == 1) {
#pragma unroll
            for (int bb = 0; bb < 4; ++bb) {
                float lg = 0.f;
#pragma unroll
                for (int oo = 0; oo < 8; ++oo) lg = fmaf(u[bb][oo], v_r[bb][oo], lg);
                lg += __shfl_xor(lg, 32);            // other o-half
                const float e = __expf(lg);          // |lg| small: max-sub unneeded
                float ssum = dpp_row_sum16(e);
                ssum += swz_xor16(ssum);
                const float c = e * __builtin_amdgcn_rcpf(ssum);
#pragma unroll
                for (int oo = 0; oo < 8; ++oo)
                    s_acc[bb][oo] = fmaf(c, u[bb][oo], s_acc[bb][oo]);
            }
        }

        cur = (cur == 2) ? 0 : cur + 1;
    }
#undef STAGE_W
#undef STAGE_ONE
#undef WAIT_PIPE

    // ---- contiguous per-block partial tile ----
    const int slab = bg * 256 + ichunk;
    float4* p4 = (float4*)(part + (size_t)slab * 8192);
#pragma unroll
    for (int bb = 0; bb < 4; ++bb) {
        const int off = ((bq4 * 4 + bb) * 512 + kk * 16 + oh * 8) >> 2;
        float4 st0 = {s_acc[bb][0], s_acc[bb][1], s_acc[bb][2], s_acc[bb][3]};
        float4 st1 = {s_acc[bb][4], s_acc[bb][5], s_acc[bb][6], s_acc[bb][7]};
        p4[off]     = st0;
        p4[off + 1] = st1;
    }
}

// ---------------------------------------------------------------------------
// Reduce 256 partial slabs per output element + fused squash / v production.
// ---------------------------------------------------------------------------
template<int RMODE>
__global__ __launch_bounds__(256)
void caps_reduce(const float* __restrict__ part,
                 const float* __restrict__ S0red,
                 float* __restrict__ S0out,
                 float* __restrict__ Vout)
{
    __shared__ float red[4][64];
    const int t   = threadIdx.x;
    const int jl  = t & 63;
    const int qc  = t >> 6;
    const int jb  = blockIdx.x * 64;
    const int j   = jb + jl;
    const int bg  = j >> 13;
    const int loc = j & 8191;
    const float* p = part + ((size_t)(bg * 256 + qc * 64)) * 8192 + loc;
    float sum = 0.f;
#pragma unroll 8
    for (int ic = 0; ic < 64; ++ic) sum += p[(size_t)ic * 8192];
    red[qc][jl] = sum;
    __syncthreads();
    if (t < 64) {
        const int jj = jb + t;
        float total = red[0][t] + red[1][t] + red[2][t] + red[3][t];
        if constexpr (RMODE == 0) {
            S0out[jj] = total;
            float val = total * (1.0f / 32.0f);
            float sq = val * val;
#pragma unroll
            for (int mask = 8; mask >= 1; mask >>= 1) sq += __shfl_xor(sq, mask);
            const float sc = sqrtf(sq) / (1.0f + sq);
            Vout[jj] = val * sc;
        } else if constexpr (RMODE == 1) {
            float val0 = S0red[jj] * (1.0f / 32.0f);
            float sq0 = val0 * val0;
#pragma unroll
            for (int mask = 8; mask >= 1; mask >>= 1) sq0 += __shfl_xor(sq0, mask);
            const float sc0 = sqrtf(sq0) / (1.0f + sq0);
            float sq1 = total * total;
#pragma unroll
            for (int mask = 8; mask >= 1; mask >>= 1) sq1 += __shfl_xor(sq1, mask);
            const float sc1 = sqrtf(sq1) / (1.0f + sq1);
            Vout[jj] = fmaf(val0, sc0, total * sc1);
        } else {
            float sq = total * total;
#pragma unroll
            for (int mask = 8; mask >= 1; mask >>= 1) sq += __shfl_xor(sq, mask);
            const float sc = sqrtf(sq) / (1.0f + sq);
            Vout[jj] = total * sc;
        }
    }
}

// ===========================================================================
// Fallback (small ws): proven R1-style f32 atomic path.
// ===========================================================================
template<int VMODE>
__global__ __launch_bounds__(256, 4)
void caps_pass_f32(const float* __restrict__ X,
                   const float* __restrict__ Wg,
                   const float* __restrict__ S0,
                   const float* __restrict__ S1,
                   float* __restrict__ Sout)
{
    constexpr int IC = 8;
    __shared__ float Ws[8192];
    __shared__ float Xs[2048];

    const int t   = threadIdx.x;
    const int kk  = t & 31;
    const int oh  = (t >> 5) & 1;
    const int bq4 = t >> 6;

    const int wg     = blockIdx.x;
    const int xcd    = wg & 7;
    const int slot   = wg >> 3;
    const int ichunk = xcd * 32 + (slot >> 2);
    const int bg     = slot & 3;
    const int i0 = ichunk * IC;
    const int b0 = bg * 16;

    float s_acc[4][8];
#pragma unroll
    for (int bb = 0; bb < 4; ++bb)
#pragma unroll
        for (int o = 0; o < 8; ++o) s_acc[bb][o] = 0.f;

    float v_r[4][8];
    if constexpr (VMODE >= 1) {
#pragma unroll
        for (int bb = 0; bb < 4; ++bb) {
            const int b = b0 + bq4 * 4 + bb;
            const float* p0 = S0 + ((size_t)b * NK + kk) * 16 + oh * 8;
            float4 a = *(const float4*)(p0);
            float4 c = *(const float4*)(p0 + 4);
            float val0[8] = {a.x,a.y,a.z,a.w,c.x,c.y,c.z,c.w};
            float sq0 = 0.f;
#pragma unroll
            for (int o = 0; o < 8; ++o) { val0[o] *= (1.0f/32.0f); sq0 = fmaf(val0[o], val0[o], sq0); }
            sq0 += __shfl_xor(sq0, 32);
            const float sc0 = sqrtf(sq0) / (1.0f + sq0);
#pragma unroll
            for (int o = 0; o < 8; ++o) v_r[bb][o] = val0[o] * sc0;
            if constexpr (VMODE == 2) {
                const float* p1 = S1 + ((size_t)b * NK + kk) * 16 + oh * 8;
                float4 a1 = *(const float4*)(p1);
                float4 c1 = *(const float4*)(p1 + 4);
                float val1[8] = {a1.x,a1.y,a1.z,a1.w,c1.x,c1.y,c1.z,c1.w};
                float sq1 = 0.f;
#pragma unroll
                for (int o = 0; o < 8; ++o) sq1 = fmaf(val1[o], val1[o], sq1);
                sq1 += __shfl_xor(sq1, 32);
                const float sc1 = sqrtf(sq1) / (1.0f + sq1);
#pragma unroll
                for (int o = 0; o < 8; ++o) v_r[bb][o] = fmaf(val1[o], sc1, v_r[bb][o]);
            }
        }
    }

    {
        const int xb   = t >> 4;
        const int xig  = t & 7;
        const int half = (t >> 3) & 1;
        const float* xp = X + (size_t)(b0 + xb) * (NI * ND) + (size_t)(i0 + xig) * ND + half * 8;
        float4 f0 = *(const float4*)(xp);
        float4 f1 = *(const float4*)(xp + 4);
        float vals[8] = {f0.x,f0.y,f0.z,f0.w,f1.x,f1.y,f1.z,f1.w};
        const int m = (xig & 7) << 3;
#pragma unroll
        for (int jj = 0; jj < 8; ++jj) {
            const int d = half * 8 + jj;
            Xs[xig * 256 + ((16 * d + xb) ^ m)] = vals[jj];
        }
    }

    for (int ii = 0; ii < IC; ++ii) {
        const int i = i0 + ii;
        __syncthreads();
        {
            const float4* wsrc = (const float4*)(Wg + (size_t)i * 8192);
#pragma unroll
            for (int j = 0; j < 8; ++j) {
                float4 val = wsrc[t + j * 256];
                const int k = (t >> 6) + 4 * j;
                ((float4*)Ws)[k * 64 + ((t & 63) ^ (k & 7))] = val;
            }
        }
        __syncthreads();

        const int xm = (ii & 7) << 3;
        float u[4][8];
        if constexpr (VMODE >= 1) {
#pragma unroll
            for (int bb = 0; bb < 4; ++bb)
#pragma unroll
                for (int o = 0; o < 8; ++o) u[bb][o] = 0.f;
        }
#pragma unroll
        for (int d = 0; d < 16; ++d) {
            const float4 x4 = *(const float4*)(&Xs[ii * 256 + ((16 * d + 4 * bq4) ^ xm)]);
            float wvv[8];
            {
                const float4 wA = ((const float4*)Ws)[kk * 64 + ((d * 4 + oh * 2)     ^ (kk & 7))];
                const float4 wB = ((const float4*)Ws)[kk * 64 + ((d * 4 + oh * 2 + 1) ^ (kk & 7))];
                wvv[0]=wA.x; wvv[1]=wA.y; wvv[2]=wA.z; wvv[3]=wA.w;
                wvv[4]=wB.x; wvv[5]=wB.y; wvv[6]=wB.z; wvv[7]=wB.w;
            }
            if constexpr (VMODE >= 1) {
#pragma unroll
                for (int o = 0; o < 8; ++o) {
                    u[0][o] = fmaf(x4.x, wvv[o], u[0][o]);
                    u[1][o] = fmaf(x4.y, wvv[o], u[1][o]);
                    u[2][o] = fmaf(x4.z, wvv[o], u[2][o]);
                    u[3][o] = fmaf(x4.w, wvv[o], u[3][o]);
                }
            } else {
#pragma unroll
                for (int o = 0; o < 8; ++o) {
                    s_acc[0][o] = fmaf(x4.x, wvv[o], s_acc[0][o]);
                    s_acc[1][o] = fmaf(x4.y, wvv[o], s_acc[1][o]);
                    s_acc[2][o] = fmaf(x4.z, wvv[o], s_acc[2][o]);
                    s_acc[3][o] = fmaf(x4.w, wvv[o], s_acc[3][o]);
                }
            }
        }

        if constexpr (VMODE >= 1) {
#pragma unroll
            for (int bb = 0; bb < 4; ++bb) {
                float lg = 0.f;
#pragma unroll
                for (int o = 0; o < 8; ++o) lg = fmaf(u[bb][o], v_r[bb][o], lg);
                lg += __shfl_xor(lg, 32);
                float m = lg;
#pragma unroll
                for (int mask = 16; mask >= 1; mask >>= 1)
                    m = fmaxf(m, __shfl_xor(m, mask));
                const float e = __expf(lg - m);
                float ssum = e;
#pragma unroll
                for (int mask = 16; mask >= 1; mask >>= 1)
                    ssum += __shfl_xor(ssum, mask);
                const float c = e / ssum;
#pragma unroll
                for (int o = 0; o < 8; ++o)
                    s_acc[bb][o] = fmaf(c, u[bb][o], s_acc[bb][o]);
            }
        }
    }

#pragma unroll
    for (int bb = 0; bb < 4; ++bb) {
        float* sp = Sout + ((size_t)(b0 + bq4 * 4 + bb) * NK + kk) * 16 + oh * 8;
#pragma unroll
        for (int o = 0; o < 8; ++o) atomicAdd(sp + o, s_acc[bb][o]);
    }
}

__global__ __launch_bounds__(256)
void squash_kernel(const float* __restrict__ S, float* __restrict__ Vout)
{
    const int idx = blockIdx.x * 256 + threadIdx.x;
    float val = S[idx];
    float sq = val * val;
#pragma unroll
    for (int mask = 8; mask >= 1; mask >>= 1) sq += __shfl_xor(sq, mask);
    const float sc = sqrtf(sq) / (1.0f + sq);
    Vout[idx] = val * sc;
}

extern "C" void kernel_launch(void* const* d_in, const int* in_sizes, int n_in,
                              void* d_out, int out_size, void* d_ws, size_t ws_size,
                              hipStream_t stream)
{
    const float* X  = (const float*)d_in[0];   // [64][2048][16]
    const float* Wg = (const float*)d_in[1];   // [2048][32][16][16]
    float* out = (float*)d_out;                // [64][32][16]

    const size_t WHU  = (size_t)2048 * 4096;        // u32
    const size_t XHU  = (size_t)64 * 2048 * 8;      // u32
    const size_t PART = (size_t)1024 * 8192;        // f32
    const size_t need = (WHU + XHU) * 4 + (PART + 3 * 32768) * 4;  // ~68.4 MB

    const dim3 blk(256), pgrid(1024), rgrid(512);

    if (ws_size >= need) {
        uint32_t* Wh = (uint32_t*)d_ws;
        uint32_t* Xh = Wh + WHU;
        float* part  = (float*)(Xh + XHU);
        float* s0    = part + PART;
        float* v0    = s0 + 32768;
        float* v01   = v0 + 32768;

        conv_w<<<dim3(2048), blk, 0, stream>>>(Wg, Wh);
        conv_x<<<dim3(1024), blk, 0, stream>>>(X, Xh);

        caps_pass_h<0><<<pgrid, blk, 0, stream>>>(Xh, Wh, nullptr, part);
        caps_reduce<0><<<rgrid, blk, 0, stream>>>(part, nullptr, s0, v0);
        caps_pass_h<1><<<pgrid, blk, 0, stream>>>(Xh, Wh, v0, part);
        caps_reduce<1><<<rgrid, blk, 0, stream>>>(part, s0, nullptr, v01);
        caps_pass_h<1><<<pgrid, blk, 0, stream>>>(Xh, Wh, v01, part);
        caps_reduce<2><<<rgrid, blk, 0, stream>>>(part, nullptr, nullptr, out);
    } else {
        // fallback: f32 atomic path
        float* s0 = (float*)d_ws;
        float* s1 = s0 + 32768;
        float* s2 = s1 + 32768;
        hipMemsetAsync(d_ws, 0, (size_t)3 * 32768 * sizeof(float), stream);
        caps_pass_f32<0><<<pgrid, blk, 0, stream>>>(X, Wg, nullptr, nullptr, s0);
        caps_pass_f32<1><<<pgrid, blk, 0, stream>>>(X, Wg, s0, nullptr, s1);
        caps_pass_f32<2><<<pgrid, blk, 0, stream>>>(X, Wg, s0, s1, s2);
        squash_kernel<<<dim3(128), blk, 0, stream>>>(s2, out);
    }
}

// Round 8
// 115.475 us; speedup vs baseline: 8.4745x; 1.2822x over previous
//
#include <hip/hip_runtime.h>
#include <math.h>
#include <stdint.h>

// Problem constants
#define NB 64       // batch
#define NI 2048     // input capsules
#define NK 32       // output capsules
#define ND 16       // in_dim = out_dim

typedef _Float16 h2t   __attribute__((ext_vector_type(2)));
typedef _Float16 f16x4 __attribute__((ext_vector_type(4)));
typedef float    f32x4 __attribute__((ext_vector_type(4)));

#if defined(__has_builtin)
#if __has_builtin(__builtin_amdgcn_global_load_lds)
#define HAVE_GLL 1
#endif
#endif
#ifndef HAVE_GLL
#define HAVE_GLL 0
#endif

static __device__ __forceinline__ uint32_t pack_h2(float a, float b) {
    h2t p; p.x = (_Float16)a; p.y = (_Float16)b;
    return __builtin_bit_cast(uint32_t, p);
}

// lane ^ 16 exchange (within 32-lane halves) on the DS pipe
static __device__ __forceinline__ float swz_xor16(float x) {
    int v = __builtin_amdgcn_ds_swizzle(__builtin_bit_cast(int, x), 0x401F);
    return __builtin_bit_cast(float, v);
}
// full reduction over the 4 lane-quadrant groups (o-fragments)
static __device__ __forceinline__ float xreduce_o(float p) {
    p += swz_xor16(p);        // q ^= 1
    p += __shfl_xor(p, 32);   // q ^= 2
    return p;
}

// ---------------------------------------------------------------------------
// conv_w: W f32 [2048][32][16][16] -> MFMA A-fragment-ordered f16 units.
// Unit (8B) at Wh2[i*2048 + T*64 + l] = { W[i][T][4q+j][r] : j=0..3 } f16,
// q=l>>4, r=l&15  (A[m=o][k=d] layout for v_mfma_f32_16x16x16f16).
// ---------------------------------------------------------------------------
__global__ __launch_bounds__(256)
void conv_w(const float* __restrict__ Wg, uint32_t* __restrict__ Wh)
{
    __shared__ float tile[32 * 264];
    const int i = blockIdx.x;           // 0..2047
    const int t = threadIdx.x;
    const float4* src = (const float4*)(Wg + (size_t)i * 8192);
#pragma unroll
    for (int j = 0; j < 8; ++j) {
        const int f4 = t + j * 256;
        const int k  = f4 >> 6;
        const int r4 = f4 & 63;
        *(float4*)(&tile[k * 264 + r4 * 4]) = src[f4];
    }
    __syncthreads();
    const int T  = t >> 3;              // 0..31 (k-tile)
    const int l0 = (t & 7) * 8;
    const float* s = tile + T * 264;
    uint2* dst = (uint2*)(Wh + (size_t)i * 4096) + T * 64 + l0;
#pragma unroll
    for (int n = 0; n < 8; ++n) {
        const int l = l0 + n;
        const int q = l >> 4, r = l & 15;
        uint2 u;
        u.x = pack_h2(s[(4 * q + 0) * 16 + r], s[(4 * q + 1) * 16 + r]);
        u.y = pack_h2(s[(4 * q + 2) * 16 + r], s[(4 * q + 3) * 16 + r]);
        dst[n] = u;
    }
}

// ---------------------------------------------------------------------------
// conv_x: X f32 [64][2048][16] -> XT f16 d-pair-packed, transposed [2048][64][8].
// ---------------------------------------------------------------------------
__global__ __launch_bounds__(256)
void conv_x(const float* __restrict__ X, uint32_t* __restrict__ XT)
{
    const int g = blockIdx.x * 256 + threadIdx.x;   // 0..131071
    const int b = g >> 11, i = g & 2047;
    const float4* src = (const float4*)(X + ((size_t)b * 2048 + i) * 16);
    const float4 f0 = src[0], f1 = src[1], f2 = src[2], f3 = src[3];
    uint4 o0, o1;
    o0.x = pack_h2(f0.x, f0.y); o0.y = pack_h2(f0.z, f0.w);
    o0.z = pack_h2(f1.x, f1.y); o0.w = pack_h2(f1.z, f1.w);
    o1.x = pack_h2(f2.x, f2.y); o1.y = pack_h2(f2.z, f2.w);
    o1.z = pack_h2(f3.x, f3.y); o1.w = pack_h2(f3.z, f3.w);
    uint4* dst = (uint4*)(XT + (size_t)i * 512 + b * 8);
    dst[0] = o0; dst[1] = o1;
}

// ---------------------------------------------------------------------------
// MFMA fused routing pass. Ring-3 W staging (global_load_lds, counted vmcnt).
// Per i: u_hat tile via v_mfma_f32_16x16x16f16:
//   A = W_i^T frag (rows o, K=d), B = X^T frag (K=d, cols b) -> D[o][b].
// Wave w owns k-tiles [8w, 8w+8). C-regs: lane(q=l>>4, r=l&15):
//   u[t][reg] = u_hat[b=r][k=8w+t][o=4q+reg].
// VMODE=0: s_acc = mfma-accumulate over i (1 barrier/iter).
// VMODE=1: logit p[t]=dot4(u,v); o-reduce (swz16+shfl32); e=exp;
//   per-wave esum partial -> Ep LDS -> raw lgkm barrier -> softmax -> s_acc.
// ---------------------------------------------------------------------------
template<int VMODE>
__global__ __launch_bounds__(256, 3)
void caps_pass_m(const uint32_t* __restrict__ XT,   // [2048][64][8] u32
                 const uint32_t* __restrict__ Wh,   // [2048][4096] u32 frag tiles
                 const float* __restrict__ V,       // [64][32][16] (VMODE=1)
                 float* __restrict__ part)
{
    constexpr int IC = 8;
    __shared__ uint32_t Ws[3][4096];   // 3 x 16 KB W ring
    __shared__ uint32_t Xs[1024];      // [ig][b][dp] 4 KB
    __shared__ float    Ep[2][4][16];  // per-wave esum partials, dbuf

    const int t = threadIdx.x;
    const int l = t & 63;
    const int w = t >> 6;              // wave id -> k-tiles [8w, 8w+8)
    const int r = l & 15;              // b-in-block (C col / A row index field)
    const int q = l >> 4;              // k-quad (C row quad / frag K-group)

    const int wg     = blockIdx.x;
    const int xcd    = wg & 7;
    const int slot   = wg >> 3;
    const int ichunk = xcd * 32 + (slot >> 2);   // 0..255
    const int bg     = slot & 3;
    const int i0 = ichunk * IC;
    const int b0 = bg * 16;

    f32x4 s_acc[8];
#pragma unroll
    for (int tt = 0; tt < 8; ++tt) s_acc[tt] = (f32x4){0.f, 0.f, 0.f, 0.f};

    f32x4 v_r[8];
    if constexpr (VMODE == 1) {
#pragma unroll
        for (int tt = 0; tt < 8; ++tt)
            v_r[tt] = *(const f32x4*)(V + ((size_t)(b0 + r) * NK + (8 * w + tt)) * 16 + 4 * q);
    }

    // ---- stage X chunk: Xs[ig][b][dp] (4 KB) ----
    {
        const int ig = t >> 5, uu = t & 31;
        uint4 v = *(const uint4*)(XT + (size_t)(i0 + ig) * 512 + b0 * 8 + uu * 4);
        *(uint4*)&Xs[ig * 128 + uu * 4] = v;
    }

#define STAGE_W(buf, tile)                                                     \
    {                                                                          \
        const size_t ibase_ = (size_t)(tile) * 4096;                           \
        _Pragma("unroll")                                                      \
        for (int j = 0; j < 4; ++j) {                                          \
            const int p = w * 4 + j;                                           \
            STAGE_ONE(buf, ibase_, p)                                          \
        }                                                                      \
    }
#if HAVE_GLL
#define STAGE_ONE(buf, ibase_, p)                                              \
    __builtin_amdgcn_global_load_lds(                                          \
        (const __attribute__((address_space(1))) void*)(Wh + ibase_ + (p) * 256 + l * 4), \
        (__attribute__((address_space(3))) void*)&Ws[buf][(p) * 256], 16, 0, 0);
#define BAR_W(n) asm volatile("s_waitcnt vmcnt(" #n ")\ns_barrier" ::: "memory");
#else
#define STAGE_ONE(buf, ibase_, p)                                              \
    ((uint4*)&Ws[buf][(p) * 256])[l] = *(const uint4*)(Wh + ibase_ + (p) * 256 + l * 4);
#define BAR_W(n) asm volatile("s_waitcnt vmcnt(0) lgkmcnt(0)\ns_barrier" ::: "memory");
#endif
#define BAR_E() asm volatile("s_waitcnt lgkmcnt(0)\ns_barrier" ::: "memory");

    __syncthreads();   // Xs visible; clean vmcnt point

    // prologue: tiles i0, i0+1
    STAGE_W(0, i0)
    STAGE_W(1, i0 + 1)

    int cur = 0;
    for (int ii = 0; ii < IC; ++ii) {
        if (ii + 1 < IC) { BAR_W(4) } else { BAR_W(0) }

        if (ii + 2 < IC) {
            const int nslot = (cur + 2 >= 3) ? cur - 1 : cur + 2;
            STAGE_W(nslot, i0 + ii + 2)
        }

        // ---- fragments ----
        const f16x4 xb = *(const f16x4*)&Xs[ii * 128 + r * 8 + q * 2];

        if constexpr (VMODE == 0) {
#pragma unroll
            for (int tt = 0; tt < 8; ++tt) {
                const f16x4 a = *(const f16x4*)&Ws[cur][(w * 8 + tt) * 128 + l * 2];
                s_acc[tt] = __builtin_amdgcn_mfma_f32_16x16x16f16(a, xb, s_acc[tt], 0, 0, 0);
            }
        } else {
            f32x4 um[8];
#pragma unroll
            for (int tt = 0; tt < 8; ++tt) {
                const f16x4 a = *(const f16x4*)&Ws[cur][(w * 8 + tt) * 128 + l * 2];
                um[tt] = __builtin_amdgcn_mfma_f32_16x16x16f16(
                    a, xb, (f32x4){0.f, 0.f, 0.f, 0.f}, 0, 0, 0);
            }
            // ---- logits + exp + per-wave esum partial ----
            float e[8];
            float esp = 0.f;
#pragma unroll
            for (int tt = 0; tt < 8; ++tt) {
                float p = um[tt][0] * v_r[tt][0];
                p = fmaf(um[tt][1], v_r[tt][1], p);
                p = fmaf(um[tt][2], v_r[tt][2], p);
                p = fmaf(um[tt][3], v_r[tt][3], p);
                p = xreduce_o(p);                 // full sum over o
                e[tt] = __expf(p);                // |lg| small: no max-sub
                esp += e[tt];
            }
            if (q == 0) Ep[ii & 1][w][r] = esp;
            BAR_E();                              // lgkm only: W prefetch stays in flight
            const float es = Ep[ii & 1][0][r] + Ep[ii & 1][1][r]
                           + Ep[ii & 1][2][r] + Ep[ii & 1][3][r];
            const float ci = __builtin_amdgcn_rcpf(es);
#pragma unroll
            for (int tt = 0; tt < 8; ++tt) {
                const float c = e[tt] * ci;
                s_acc[tt][0] = fmaf(c, um[tt][0], s_acc[tt][0]);
                s_acc[tt][1] = fmaf(c, um[tt][1], s_acc[tt][1]);
                s_acc[tt][2] = fmaf(c, um[tt][2], s_acc[tt][2]);
                s_acc[tt][3] = fmaf(c, um[tt][3], s_acc[tt][3]);
            }
        }
        cur = (cur == 2) ? 0 : cur + 1;
    }
#undef STAGE_W
#undef STAGE_ONE
#undef BAR_W
#undef BAR_E

    // ---- store partial tile: part[slab][b=r][k=8w+tt][o=4q+reg] ----
    float* base = part + (size_t)(bg * 256 + ichunk) * 8192 + r * 512 + 4 * q;
#pragma unroll
    for (int tt = 0; tt < 8; ++tt) {
        float4 st = {s_acc[tt][0], s_acc[tt][1], s_acc[tt][2], s_acc[tt][3]};
        *(float4*)(base + (8 * w + tt) * 16) = st;
    }
}

// ---------------------------------------------------------------------------
// Reduce 256 partial slabs per output element + fused squash / v production.
// RMODE=0: s0 = sum; store s0; v0 = squash(s0/32)
// RMODE=1: v01 = squash(S0red/32) + squash(sum)
// RMODE=2: out = squash(sum)
// ---------------------------------------------------------------------------
template<int RMODE>
__global__ __launch_bounds__(256)
void caps_reduce(const float* __restrict__ part,
                 const float* __restrict__ S0red,
                 float* __restrict__ S0out,
                 float* __restrict__ Vout)
{
    __shared__ float red[4][64];
    const int t   = threadIdx.x;
    const int jl  = t & 63;
    const int qc  = t >> 6;
    const int jb  = blockIdx.x * 64;
    const int j   = jb + jl;
    const int bg  = j >> 13;
    const int loc = j & 8191;
    const float* p = part + ((size_t)(bg * 256 + qc * 64)) * 8192 + loc;
    float sum = 0.f;
#pragma unroll 8
    for (int ic = 0; ic < 64; ++ic) sum += p[(size_t)ic * 8192];
    red[qc][jl] = sum;
    __syncthreads();
    if (t < 64) {
        const int jj = jb + t;
        float total = red[0][t] + red[1][t] + red[2][t] + red[3][t];
        if constexpr (RMODE == 0) {
            S0out[jj] = total;
            float val = total * (1.0f / 32.0f);
            float sq = val * val;
#pragma unroll
            for (int mask = 8; mask >= 1; mask >>= 1) sq += __shfl_xor(sq, mask);
            const float sc = sqrtf(sq) / (1.0f + sq);
            Vout[jj] = val * sc;
        } else if constexpr (RMODE == 1) {
            float val0 = S0red[jj] * (1.0f / 32.0f);
            float sq0 = val0 * val0;
#pragma unroll
            for (int mask = 8; mask >= 1; mask >>= 1) sq0 += __shfl_xor(sq0, mask);
            const float sc0 = sqrtf(sq0) / (1.0f + sq0);
            float sq1 = total * total;
#pragma unroll
            for (int mask = 8; mask >= 1; mask >>= 1) sq1 += __shfl_xor(sq1, mask);
            const float sc1 = sqrtf(sq1) / (1.0f + sq1);
            Vout[jj] = fmaf(val0, sc0, total * sc1);
        } else {
            float sq = total * total;
#pragma unroll
            for (int mask = 8; mask >= 1; mask >>= 1) sq += __shfl_xor(sq, mask);
            const float sc = sqrtf(sq) / (1.0f + sq);
            Vout[jj] = total * sc;
        }
    }
}

// ===========================================================================
// Fallback (small ws): proven R1-style f32 atomic path.
// ===========================================================================
template<int VMODE>
__global__ __launch_bounds__(256, 4)
void caps_pass_f32(const float* __restrict__ X,
                   const float* __restrict__ Wg,
                   const float* __restrict__ S0,
                   const float* __restrict__ S1,
                   float* __restrict__ Sout)
{
    constexpr int IC = 8;
    __shared__ float Ws[8192];
    __shared__ float Xs[2048];

    const int t   = threadIdx.x;
    const int kk  = t & 31;
    const int oh  = (t >> 5) & 1;
    const int bq4 = t >> 6;

    const int wg     = blockIdx.x;
    const int xcd    = wg & 7;
    const int slot   = wg >> 3;
    const int ichunk = xcd * 32 + (slot >> 2);
    const int bg     = slot & 3;
    const int i0 = ichunk * IC;
    const int b0 = bg * 16;

    float s_acc[4][8];
#pragma unroll
    for (int bb = 0; bb < 4; ++bb)
#pragma unroll
        for (int o = 0; o < 8; ++o) s_acc[bb][o] = 0.f;

    float v_r[4][8];
    if constexpr (VMODE >= 1) {
#pragma unroll
        for (int bb = 0; bb < 4; ++bb) {
            const int b = b0 + bq4 * 4 + bb;
            const float* p0 = S0 + ((size_t)b * NK + kk) * 16 + oh * 8;
            float4 a = *(const float4*)(p0);
            float4 c = *(const float4*)(p0 + 4);
            float val0[8] = {a.x,a.y,a.z,a.w,c.x,c.y,c.z,c.w};
            float sq0 = 0.f;
#pragma unroll
            for (int o = 0; o < 8; ++o) { val0[o] *= (1.0f/32.0f); sq0 = fmaf(val0[o], val0[o], sq0); }
            sq0 += __shfl_xor(sq0, 32);
            const float sc0 = sqrtf(sq0) / (1.0f + sq0);
#pragma unroll
            for (int o = 0; o < 8; ++o) v_r[bb][o] = val0[o] * sc0;
            if constexpr (VMODE == 2) {
                const float* p1 = S1 + ((size_t)b * NK + kk) * 16 + oh * 8;
                float4 a1 = *(const float4*)(p1);
                float4 c1 = *(const float4*)(p1 + 4);
                float val1[8] = {a1.x,a1.y,a1.z,a1.w,c1.x,c1.y,c1.z,c1.w};
                float sq1 = 0.f;
#pragma unroll
                for (int o = 0; o < 8; ++o) sq1 = fmaf(val1[o], val1[o], sq1);
                sq1 += __shfl_xor(sq1, 32);
                const float sc1 = sqrtf(sq1) / (1.0f + sq1);
#pragma unroll
                for (int o = 0; o < 8; ++o) v_r[bb][o] = fmaf(val1[o], sc1, v_r[bb][o]);
            }
        }
    }

    {
        const int xb   = t >> 4;
        const int xig  = t & 7;
        const int half = (t >> 3) & 1;
        const float* xp = X + (size_t)(b0 + xb) * (NI * ND) + (size_t)(i0 + xig) * ND + half * 8;
        float4 f0 = *(const float4*)(xp);
        float4 f1 = *(const float4*)(xp + 4);
        float vals[8] = {f0.x,f0.y,f0.z,f0.w,f1.x,f1.y,f1.z,f1.w};
        const int m = (xig & 7) << 3;
#pragma unroll
        for (int jj = 0; jj < 8; ++jj) {
            const int d = half * 8 + jj;
            Xs[xig * 256 + ((16 * d + xb) ^ m)] = vals[jj];
        }
    }

    for (int ii = 0; ii < IC; ++ii) {
        const int i = i0 + ii;
        __syncthreads();
        {
            const float4* wsrc = (const float4*)(Wg + (size_t)i * 8192);
#pragma unroll
            for (int j = 0; j < 8; ++j) {
                float4 val = wsrc[t + j * 256];
                const int k = (t >> 6) + 4 * j;
                ((float4*)Ws)[k * 64 + ((t & 63) ^ (k & 7))] = val;
            }
        }
        __syncthreads();

        const int xm = (ii & 7) << 3;
        float u[4][8];
        if constexpr (VMODE >= 1) {
#pragma unroll
            for (int bb = 0; bb < 4; ++bb)
#pragma unroll
                for (int o = 0; o < 8; ++o) u[bb][o] = 0.f;
        }
#pragma unroll
        for (int d = 0; d < 16; ++d) {
            const float4 x4 = *(const float4*)(&Xs[ii * 256 + ((16 * d + 4 * bq4) ^ xm)]);
            float wvv[8];
            {
                const float4 wA = ((const float4*)Ws)[kk * 64 + ((d * 4 + oh * 2)     ^ (kk & 7))];
                const float4 wB = ((const float4*)Ws)[kk * 64 + ((d * 4 + oh * 2 + 1) ^ (kk & 7))];
                wvv[0]=wA.x; wvv[1]=wA.y; wvv[2]=wA.z; wvv[3]=wA.w;
                wvv[4]=wB.x; wvv[5]=wB.y; wvv[6]=wB.z; wvv[7]=wB.w;
            }
            if constexpr (VMODE >= 1) {
#pragma unroll
                for (int o = 0; o < 8; ++o) {
                    u[0][o] = fmaf(x4.x, wvv[o], u[0][o]);
                    u[1][o] = fmaf(x4.y, wvv[o], u[1][o]);
                    u[2][o] = fmaf(x4.z, wvv[o], u[2][o]);
                    u[3][o] = fmaf(x4.w, wvv[o], u[3][o]);
                }
            } else {
#pragma unroll
                for (int o = 0; o < 8; ++o) {
                    s_acc[0][o] = fmaf(x4.x, wvv[o], s_acc[0][o]);
                    s_acc[1][o] = fmaf(x4.y, wvv[o], s_acc[1][o]);
                    s_acc[2][o] = fmaf(x4.z, wvv[o], s_acc[2][o]);
                    s_acc[3][o] = fmaf(x4.w, wvv[o], s_acc[3][o]);
                }
            }
        }

        if constexpr (VMODE >= 1) {
#pragma unroll
            for (int bb = 0; bb < 4; ++bb) {
                float lg = 0.f;
#pragma unroll
                for (int o = 0; o < 8; ++o) lg = fmaf(u[bb][o], v_r[bb][o], lg);
                lg += __shfl_xor(lg, 32);
                float m = lg;
#pragma unroll
                for (int mask = 16; mask >= 1; mask >>= 1)
                    m = fmaxf(m, __shfl_xor(m, mask));
                const float e = __expf(lg - m);
                float ssum = e;
#pragma unroll
                for (int mask = 16; mask >= 1; mask >>= 1)
                    ssum += __shfl_xor(ssum, mask);
                const float c = e / ssum;
#pragma unroll
                for (int o = 0; o < 8; ++o)
                    s_acc[bb][o] = fmaf(c, u[bb][o], s_acc[bb][o]);
            }
        }
    }

#pragma unroll
    for (int bb = 0; bb < 4; ++bb) {
        float* sp = Sout + ((size_t)(b0 + bq4 * 4 + bb) * NK + kk) * 16 + oh * 8;
#pragma unroll
        for (int o = 0; o < 8; ++o) atomicAdd(sp + o, s_acc[bb][o]);
    }
}

__global__ __launch_bounds__(256)
void squash_kernel(const float* __restrict__ S, float* __restrict__ Vout)
{
    const int idx = blockIdx.x * 256 + threadIdx.x;
    float val = S[idx];
    float sq = val * val;
#pragma unroll
    for (int mask = 8; mask >= 1; mask >>= 1) sq += __shfl_xor(sq, mask);
    const float sc = sqrtf(sq) / (1.0f + sq);
    Vout[idx] = val * sc;
}

extern "C" void kernel_launch(void* const* d_in, const int* in_sizes, int n_in,
                              void* d_out, int out_size, void* d_ws, size_t ws_size,
                              hipStream_t stream)
{
    const float* X  = (const float*)d_in[0];   // [64][2048][16]
    const float* Wg = (const float*)d_in[1];   // [2048][32][16][16]
    float* out = (float*)d_out;                // [64][32][16]

    const size_t WHU  = (size_t)2048 * 4096;        // u32
    const size_t XHU  = (size_t)64 * 2048 * 8;      // u32
    const size_t PART = (size_t)1024 * 8192;        // f32
    const size_t need = (WHU + XHU) * 4 + (PART + 3 * 32768) * 4;  // ~68.4 MB

    const dim3 blk(256), pgrid(1024), rgrid(512);

    if (ws_size >= need) {
        uint32_t* Wh = (uint32_t*)d_ws;
        uint32_t* XT = Wh + WHU;
        float* part  = (float*)(XT + XHU);
        float* s0    = part + PART;
        float* v0    = s0 + 32768;
        float* v01   = v0 + 32768;

        conv_w<<<dim3(2048), blk, 0, stream>>>(Wg, Wh);
        conv_x<<<dim3(512),  blk, 0, stream>>>(X, XT);

        caps_pass_m<0><<<pgrid, blk, 0, stream>>>(XT, Wh, nullptr, part);
        caps_reduce<0><<<rgrid, blk, 0, stream>>>(part, nullptr, s0, v0);
        caps_pass_m<1><<<pgrid, blk, 0, stream>>>(XT, Wh, v0, part);
        caps_reduce<1><<<rgrid, blk, 0, stream>>>(part, s0, nullptr, v01);
        caps_pass_m<1><<<pgrid, blk, 0, stream>>>(XT, Wh, v01, part);
        caps_reduce<2><<<rgrid, blk, 0, stream>>>(part, nullptr, nullptr, out);
    } else {
        // fallback: f32 atomic path
        float* s0 = (float*)d_ws;
        float* s1 = s0 + 32768;
        float* s2 = s1 + 32768;
        hipMemsetAsync(d_ws, 0, (size_t)3 * 32768 * sizeof(float), stream);
        caps_pass_f32<0><<<pgrid, blk, 0, stream>>>(X, Wg, nullptr, nullptr, s0);
        caps_pass_f32<1><<<pgrid, blk, 0, stream>>>(X, Wg, s0, nullptr, s1);
        caps_pass_f32<2><<<pgrid, blk, 0, stream>>>(X, Wg, s0, s1, s2);
        squash_kernel<<<dim3(128), blk, 0, stream>>>(s2, out);
    }
}

// Round 9
// 96.796 us; speedup vs baseline: 10.1098x; 1.1930x over previous
//
#include <hip/hip_runtime.h>
#include <math.h>
#include <stdint.h>

// Problem constants
#define NB 64       // batch
#define NI 2048     // input capsules
#define NK 32       // output capsules
#define ND 16       // in_dim = out_dim

typedef _Float16 h2t   __attribute__((ext_vector_type(2)));
typedef _Float16 f16x4 __attribute__((ext_vector_type(4)));
typedef float    f32x4 __attribute__((ext_vector_type(4)));

#if defined(__has_builtin)
#if __has_builtin(__builtin_amdgcn_global_load_lds)
#define HAVE_GLL 1
#endif
#endif
#ifndef HAVE_GLL
#define HAVE_GLL 0
#endif

static __device__ __forceinline__ uint32_t pack_h2(float a, float b) {
    h2t p; p.x = (_Float16)a; p.y = (_Float16)b;
    return __builtin_bit_cast(uint32_t, p);
}

// lane ^ 16 exchange (within 32-lane halves) on the DS pipe
static __device__ __forceinline__ float swz_xor16(float x) {
    int v = __builtin_amdgcn_ds_swizzle(__builtin_bit_cast(int, x), 0x401F);
    return __builtin_bit_cast(float, v);
}
// full reduction over the 4 lane-quadrant groups (o-fragments)
static __device__ __forceinline__ float xreduce_o(float p) {
    p += swz_xor16(p);        // q ^= 1
    p += __shfl_xor(p, 32);   // q ^= 2
    return p;
}

// ---------------------------------------------------------------------------
// conv_w: W f32 [2048][32][16][16] -> MFMA A-fragment-ordered f16 units.
// Unit (8B) at Wh2[i*2048 + T*64 + l] = { W[i][T][4q+j][r] : j=0..3 } f16,
// q=l>>4, r=l&15  (A[m=o][k=d] layout for v_mfma_f32_16x16x16f16).
// ---------------------------------------------------------------------------
__global__ __launch_bounds__(256)
void conv_w(const float* __restrict__ Wg, uint32_t* __restrict__ Wh)
{
    __shared__ float tile[32 * 264];
    const int i = blockIdx.x;           // 0..2047
    const int t = threadIdx.x;
    const float4* src = (const float4*)(Wg + (size_t)i * 8192);
#pragma unroll
    for (int j = 0; j < 8; ++j) {
        const int f4 = t + j * 256;
        const int k  = f4 >> 6;
        const int r4 = f4 & 63;
        *(float4*)(&tile[k * 264 + r4 * 4]) = src[f4];
    }
    __syncthreads();
    const int T  = t >> 3;              // 0..31 (k-tile)
    const int l0 = (t & 7) * 8;
    const float* s = tile + T * 264;
    uint2* dst = (uint2*)(Wh + (size_t)i * 4096) + T * 64 + l0;
#pragma unroll
    for (int n = 0; n < 8; ++n) {
        const int l = l0 + n;
        const int q = l >> 4, r = l & 15;
        uint2 u;
        u.x = pack_h2(s[(4 * q + 0) * 16 + r], s[(4 * q + 1) * 16 + r]);
        u.y = pack_h2(s[(4 * q + 2) * 16 + r], s[(4 * q + 3) * 16 + r]);
        dst[n] = u;
    }
}

// ---------------------------------------------------------------------------
// conv_x: X f32 [64][2048][16] -> XT f16 d-pair-packed, transposed [2048][64][8].
// ---------------------------------------------------------------------------
__global__ __launch_bounds__(256)
void conv_x(const float* __restrict__ X, uint32_t* __restrict__ XT)
{
    const int g = blockIdx.x * 256 + threadIdx.x;   // 0..131071
    const int b = g >> 11, i = g & 2047;
    const float4* src = (const float4*)(X + ((size_t)b * 2048 + i) * 16);
    const float4 f0 = src[0], f1 = src[1], f2 = src[2], f3 = src[3];
    uint4 o0, o1;
    o0.x = pack_h2(f0.x, f0.y); o0.y = pack_h2(f0.z, f0.w);
    o0.z = pack_h2(f1.x, f1.y); o0.w = pack_h2(f1.z, f1.w);
    o1.x = pack_h2(f2.x, f2.y); o1.y = pack_h2(f2.z, f2.w);
    o1.z = pack_h2(f3.x, f3.y); o1.w = pack_h2(f3.z, f3.w);
    uint4* dst = (uint4*)(XT + (size_t)i * 512 + b * 8);
    dst[0] = o0; dst[1] = o1;
}

// ---------------------------------------------------------------------------
// MFMA fused routing pass. Ring-3 W staging (global_load_lds, counted vmcnt).
// IC=16, grid 512 (= 2 blocks/CU, all resident, no tail).
// Per i: u_hat tile via v_mfma_f32_16x16x16f16; wave w owns k-tiles [8w,8w+8).
// C-regs lane(q=l>>4, r=l&15): u[tt][reg] = u_hat[b=r][k=8w+tt][o=4q+reg].
// VMODE=0: s_acc = mfma-accumulate over i (1 barrier/iter).
// VMODE=1: logit=dot4+o-reduce; e=exp; cross-wave esum via Ep + lgkm barrier.
// Partials stored f16-pair-packed: part_h[slab][b16][k32][op8] u32,
// slab = bg*128 + ichunk.
// ---------------------------------------------------------------------------
template<int VMODE>
__global__ __launch_bounds__(256, 2)
void caps_pass_m(const uint32_t* __restrict__ XT,   // [2048][64][8] u32
                 const uint32_t* __restrict__ Wh,   // [2048][4096] u32 frag tiles
                 const float* __restrict__ V,       // [64][32][16] (VMODE=1)
                 uint32_t* __restrict__ part_h)     // f16-pair partials
{
    constexpr int IC = 16;
    __shared__ uint32_t Ws[3][4096];   // 3 x 16 KB W ring
    __shared__ uint32_t Xs[2048];      // [ig16][b16][dp8] 8 KB
    __shared__ float    Ep[2][4][16];  // per-wave esum partials, dbuf

    const int t = threadIdx.x;
    const int l = t & 63;
    const int w = t >> 6;              // wave id -> k-tiles [8w, 8w+8)
    const int r = l & 15;              // b-in-block
    const int q = l >> 4;              // o-quad

    const int wg     = blockIdx.x;     // 0..511
    const int xcd    = wg & 7;
    const int slot   = wg >> 3;        // 0..63
    const int ichunk = xcd * 16 + (slot >> 2);   // 0..127
    const int bg     = slot & 3;
    const int i0 = ichunk * IC;
    const int b0 = bg * 16;

    f32x4 s_acc[8];
#pragma unroll
    for (int tt = 0; tt < 8; ++tt) s_acc[tt] = (f32x4){0.f, 0.f, 0.f, 0.f};

    f32x4 v_r[8];
    if constexpr (VMODE == 1) {
#pragma unroll
        for (int tt = 0; tt < 8; ++tt)
            v_r[tt] = *(const f32x4*)(V + ((size_t)(b0 + r) * NK + (8 * w + tt)) * 16 + 4 * q);
    }

    // ---- stage X chunk: Xs[ig][b][dp] (8 KB) ----
    {
        const int ig = t >> 4, uu = t & 15;
        const uint4* src = (const uint4*)(XT + (size_t)(i0 + ig) * 512 + b0 * 8);
        *(uint4*)&Xs[ig * 128 + uu * 4]        = src[uu];
        *(uint4*)&Xs[ig * 128 + (uu + 16) * 4] = src[uu + 16];
    }

#define STAGE_W(buf, tile)                                                     \
    {                                                                          \
        const size_t ibase_ = (size_t)(tile) * 4096;                           \
        _Pragma("unroll")                                                      \
        for (int j = 0; j < 4; ++j) {                                          \
            const int p = w * 4 + j;                                           \
            STAGE_ONE(buf, ibase_, p)                                          \
        }                                                                      \
    }
#if HAVE_GLL
#define STAGE_ONE(buf, ibase_, p)                                              \
    __builtin_amdgcn_global_load_lds(                                          \
        (const __attribute__((address_space(1))) void*)(Wh + ibase_ + (p) * 256 + l * 4), \
        (__attribute__((address_space(3))) void*)&Ws[buf][(p) * 256], 16, 0, 0);
#define BAR_W(n) asm volatile("s_waitcnt vmcnt(" #n ")\ns_barrier" ::: "memory");
#else
#define STAGE_ONE(buf, ibase_, p)                                              \
    ((uint4*)&Ws[buf][(p) * 256])[l] = *(const uint4*)(Wh + ibase_ + (p) * 256 + l * 4);
#define BAR_W(n) asm volatile("s_waitcnt vmcnt(0) lgkmcnt(0)\ns_barrier" ::: "memory");
#endif
#define BAR_E() asm volatile("s_waitcnt lgkmcnt(0)\ns_barrier" ::: "memory");

    __syncthreads();   // Xs visible; clean vmcnt point

    // prologue: tiles i0, i0+1
    STAGE_W(0, i0)
    STAGE_W(1, i0 + 1)

    int cur = 0;
    for (int ii = 0; ii < IC; ++ii) {
        if (ii + 1 < IC) { BAR_W(4) } else { BAR_W(0) }

        if (ii + 2 < IC) {
            const int nslot = (cur + 2 >= 3) ? cur - 1 : cur + 2;
            STAGE_W(nslot, i0 + ii + 2)
        }

        // ---- fragments ----
        const f16x4 xb = *(const f16x4*)&Xs[ii * 128 + r * 8 + q * 2];

        if constexpr (VMODE == 0) {
#pragma unroll
            for (int tt = 0; tt < 8; ++tt) {
                const f16x4 a = *(const f16x4*)&Ws[cur][(w * 8 + tt) * 128 + l * 2];
                s_acc[tt] = __builtin_amdgcn_mfma_f32_16x16x16f16(a, xb, s_acc[tt], 0, 0, 0);
            }
        } else {
            f32x4 um[8];
#pragma unroll
            for (int tt = 0; tt < 8; ++tt) {
                const f16x4 a = *(const f16x4*)&Ws[cur][(w * 8 + tt) * 128 + l * 2];
                um[tt] = __builtin_amdgcn_mfma_f32_16x16x16f16(
                    a, xb, (f32x4){0.f, 0.f, 0.f, 0.f}, 0, 0, 0);
            }
            // ---- logits + exp + per-wave esum partial ----
            float e[8];
            float esp = 0.f;
#pragma unroll
            for (int tt = 0; tt < 8; ++tt) {
                float p = um[tt][0] * v_r[tt][0];
                p = fmaf(um[tt][1], v_r[tt][1], p);
                p = fmaf(um[tt][2], v_r[tt][2], p);
                p = fmaf(um[tt][3], v_r[tt][3], p);
                p = xreduce_o(p);                 // full sum over o
                e[tt] = __expf(p);                // |lg| small: no max-sub
                esp += e[tt];
            }
            if (q == 0) Ep[ii & 1][w][r] = esp;
            BAR_E();                              // lgkm only: W prefetch stays in flight
            const float es = Ep[ii & 1][0][r] + Ep[ii & 1][1][r]
                           + Ep[ii & 1][2][r] + Ep[ii & 1][3][r];
            const float ci = __builtin_amdgcn_rcpf(es);
#pragma unroll
            for (int tt = 0; tt < 8; ++tt) {
                const float c = e[tt] * ci;
                s_acc[tt][0] = fmaf(c, um[tt][0], s_acc[tt][0]);
                s_acc[tt][1] = fmaf(c, um[tt][1], s_acc[tt][1]);
                s_acc[tt][2] = fmaf(c, um[tt][2], s_acc[tt][2]);
                s_acc[tt][3] = fmaf(c, um[tt][3], s_acc[tt][3]);
            }
        }
        cur = (cur == 2) ? 0 : cur + 1;
    }
#undef STAGE_W
#undef STAGE_ONE
#undef BAR_W
#undef BAR_E

    // ---- store f16-pair partial tile: part_h[slab][b=r][k=8w+tt][op=2q,2q+1] ----
    uint32_t* base = part_h + (size_t)(bg * 128 + ichunk) * 4096 + r * 256 + 2 * q;
#pragma unroll
    for (int tt = 0; tt < 8; ++tt) {
        uint2 st;
        st.x = pack_h2(s_acc[tt][0], s_acc[tt][1]);
        st.y = pack_h2(s_acc[tt][2], s_acc[tt][3]);
        *(uint2*)(base + (8 * w + tt) * 8) = st;
    }
}

// ---------------------------------------------------------------------------
// Reduce 128 f16-pair slabs per output pair + fused squash / v production.
// Output pair j in [0,16384): b=j>>8, k=(j>>3)&31, op=j&7 (o=2op,2op+1).
// RMODE=0: s0 = sum; store s0 (f32); v0 = squash(s0/32)
// RMODE=1: v01 = squash(S0red/32) + squash(sum)
// RMODE=2: out = squash(sum)
// Grid 256 x 256: block owns 64 pairs; thread (jl=t&63, qc=t>>6) sums 32 slabs.
// ---------------------------------------------------------------------------
template<int RMODE>
__global__ __launch_bounds__(256)
void caps_reduce(const uint32_t* __restrict__ part_h,
                 const float* __restrict__ S0red,
                 float* __restrict__ S0out,
                 float* __restrict__ Vout)
{
    __shared__ float2 red[4][64];
    const int t   = threadIdx.x;
    const int jl  = t & 63;
    const int qc  = t >> 6;
    const int jb  = blockIdx.x * 64;     // pair base
    const int j   = jb + jl;             // 0..16383
    const int b   = j >> 8;
    const int bg  = b >> 4;
    const int loc = (b & 15) * 256 + (j & 255);
    const uint32_t* p = part_h + ((size_t)(bg * 128 + qc * 32)) * 4096 + loc;
    float sx = 0.f, sy = 0.f;
#pragma unroll 8
    for (int ic = 0; ic < 32; ++ic) {
        h2t v = __builtin_bit_cast(h2t, p[(size_t)ic * 4096]);
        sx += (float)v.x; sy += (float)v.y;
    }
    red[qc][jl] = make_float2(sx, sy);
    __syncthreads();
    if (t < 64) {
        const int jj = jb + t;
        float2 a0 = red[0][t], a1 = red[1][t], a2 = red[2][t], a3 = red[3][t];
        const float tx = a0.x + a1.x + a2.x + a3.x;
        const float ty = a0.y + a1.y + a2.y + a3.y;
        if constexpr (RMODE == 0) {
            S0out[2 * jj]     = tx;
            S0out[2 * jj + 1] = ty;
            const float vx = tx * (1.0f / 32.0f), vy = ty * (1.0f / 32.0f);
            float sq = vx * vx + vy * vy;
#pragma unroll
            for (int mask = 4; mask >= 1; mask >>= 1) sq += __shfl_xor(sq, mask);
            const float sc = sqrtf(sq) / (1.0f + sq);
            Vout[2 * jj]     = vx * sc;
            Vout[2 * jj + 1] = vy * sc;
        } else if constexpr (RMODE == 1) {
            const float v0x = S0red[2 * jj] * (1.0f / 32.0f);
            const float v0y = S0red[2 * jj + 1] * (1.0f / 32.0f);
            float sq0 = v0x * v0x + v0y * v0y;
#pragma unroll
            for (int mask = 4; mask >= 1; mask >>= 1) sq0 += __shfl_xor(sq0, mask);
            const float sc0 = sqrtf(sq0) / (1.0f + sq0);
            float sq1 = tx * tx + ty * ty;
#pragma unroll
            for (int mask = 4; mask >= 1; mask >>= 1) sq1 += __shfl_xor(sq1, mask);
            const float sc1 = sqrtf(sq1) / (1.0f + sq1);
            Vout[2 * jj]     = fmaf(v0x, sc0, tx * sc1);
            Vout[2 * jj + 1] = fmaf(v0y, sc0, ty * sc1);
        } else {
            float sq = tx * tx + ty * ty;
#pragma unroll
            for (int mask = 4; mask >= 1; mask >>= 1) sq += __shfl_xor(sq, mask);
            const float sc = sqrtf(sq) / (1.0f + sq);
            Vout[2 * jj]     = tx * sc;
            Vout[2 * jj + 1] = ty * sc;
        }
    }
}

// ===========================================================================
// Fallback (small ws): proven R1-style f32 atomic path.
// ===========================================================================
template<int VMODE>
__global__ __launch_bounds__(256, 4)
void caps_pass_f32(const float* __restrict__ X,
                   const float* __restrict__ Wg,
                   const float* __restrict__ S0,
                   const float* __restrict__ S1,
                   float* __restrict__ Sout)
{
    constexpr int IC = 8;
    __shared__ float Ws[8192];
    __shared__ float Xs[2048];

    const int t   = threadIdx.x;
    const int kk  = t & 31;
    const int oh  = (t >> 5) & 1;
    const int bq4 = t >> 6;

    const int wg     = blockIdx.x;
    const int xcd    = wg & 7;
    const int slot   = wg >> 3;
    const int ichunk = xcd * 32 + (slot >> 2);
    const int bg     = slot & 3;
    const int i0 = ichunk * IC;
    const int b0 = bg * 16;

    float s_acc[4][8];
#pragma unroll
    for (int bb = 0; bb < 4; ++bb)
#pragma unroll
        for (int o = 0; o < 8; ++o) s_acc[bb][o] = 0.f;

    float v_r[4][8];
    if constexpr (VMODE >= 1) {
#pragma unroll
        for (int bb = 0; bb < 4; ++bb) {
            const int b = b0 + bq4 * 4 + bb;
            const float* p0 = S0 + ((size_t)b * NK + kk) * 16 + oh * 8;
            float4 a = *(const float4*)(p0);
            float4 c = *(const float4*)(p0 + 4);
            float val0[8] = {a.x,a.y,a.z,a.w,c.x,c.y,c.z,c.w};
            float sq0 = 0.f;
#pragma unroll
            for (int o = 0; o < 8; ++o) { val0[o] *= (1.0f/32.0f); sq0 = fmaf(val0[o], val0[o], sq0); }
            sq0 += __shfl_xor(sq0, 32);
            const float sc0 = sqrtf(sq0) / (1.0f + sq0);
#pragma unroll
            for (int o = 0; o < 8; ++o) v_r[bb][o] = val0[o] * sc0;
            if constexpr (VMODE == 2) {
                const float* p1 = S1 + ((size_t)b * NK + kk) * 16 + oh * 8;
                float4 a1 = *(const float4*)(p1);
                float4 c1 = *(const float4*)(p1 + 4);
                float val1[8] = {a1.x,a1.y,a1.z,a1.w,c1.x,c1.y,c1.z,c1.w};
                float sq1 = 0.f;
#pragma unroll
                for (int o = 0; o < 8; ++o) sq1 = fmaf(val1[o], val1[o], sq1);
                sq1 += __shfl_xor(sq1, 32);
                const float sc1 = sqrtf(sq1) / (1.0f + sq1);
#pragma unroll
                for (int o = 0; o < 8; ++o) v_r[bb][o] = fmaf(val1[o], sc1, v_r[bb][o]);
            }
        }
    }

    {
        const int xb   = t >> 4;
        const int xig  = t & 7;
        const int half = (t >> 3) & 1;
        const float* xp = X + (size_t)(b0 + xb) * (NI * ND) + (size_t)(i0 + xig) * ND + half * 8;
        float4 f0 = *(const float4*)(xp);
        float4 f1 = *(const float4*)(xp + 4);
        float vals[8] = {f0.x,f0.y,f0.z,f0.w,f1.x,f1.y,f1.z,f1.w};
        const int m = (xig & 7) << 3;
#pragma unroll
        for (int jj = 0; jj < 8; ++jj) {
            const int d = half * 8 + jj;
            Xs[xig * 256 + ((16 * d + xb) ^ m)] = vals[jj];
        }
    }

    for (int ii = 0; ii < IC; ++ii) {
        const int i = i0 + ii;
        __syncthreads();
        {
            const float4* wsrc = (const float4*)(Wg + (size_t)i * 8192);
#pragma unroll
            for (int j = 0; j < 8; ++j) {
                float4 val = wsrc[t + j * 256];
                const int k = (t >> 6) + 4 * j;
                ((float4*)Ws)[k * 64 + ((t & 63) ^ (k & 7))] = val;
            }
        }
        __syncthreads();

        const int xm = (ii & 7) << 3;
        float u[4][8];
        if constexpr (VMODE >= 1) {
#pragma unroll
            for (int bb = 0; bb < 4; ++bb)
#pragma unroll
                for (int o = 0; o < 8; ++o) u[bb][o] = 0.f;
        }
#pragma unroll
        for (int d = 0; d < 16; ++d) {
            const float4 x4 = *(const float4*)(&Xs[ii * 256 + ((16 * d + 4 * bq4) ^ xm)]);
            float wvv[8];
            {
                const float4 wA = ((const float4*)Ws)[kk * 64 + ((d * 4 + oh * 2)     ^ (kk & 7))];
                const float4 wB = ((const float4*)Ws)[kk * 64 + ((d * 4 + oh * 2 + 1) ^ (kk & 7))];
                wvv[0]=wA.x; wvv[1]=wA.y; wvv[2]=wA.z; wvv[3]=wA.w;
                wvv[4]=wB.x; wvv[5]=wB.y; wvv[6]=wB.z; wvv[7]=wB.w;
            }
            if constexpr (VMODE >= 1) {
#pragma unroll
                for (int o = 0; o < 8; ++o) {
                    u[0][o] = fmaf(x4.x, wvv[o], u[0][o]);
                    u[1][o] = fmaf(x4.y, wvv[o], u[1][o]);
                    u[2][o] = fmaf(x4.z, wvv[o], u[2][o]);
                    u[3][o] = fmaf(x4.w, wvv[o], u[3][o]);
                }
            } else {
#pragma unroll
                for (int o = 0; o < 8; ++o) {
                    s_acc[0][o] = fmaf(x4.x, wvv[o], s_acc[0][o]);
                    s_acc[1][o] = fmaf(x4.y, wvv[o], s_acc[1][o]);
                    s_acc[2][o] = fmaf(x4.z, wvv[o], s_acc[2][o]);
                    s_acc[3][o] = fmaf(x4.w, wvv[o], s_acc[3][o]);
                }
            }
        }

        if constexpr (VMODE >= 1) {
#pragma unroll
            for (int bb = 0; bb < 4; ++bb) {
                float lg = 0.f;
#pragma unroll
                for (int o = 0; o < 8; ++o) lg = fmaf(u[bb][o], v_r[bb][o], lg);
                lg += __shfl_xor(lg, 32);
                float m = lg;
#pragma unroll
                for (int mask = 16; mask >= 1; mask >>= 1)
                    m = fmaxf(m, __shfl_xor(m, mask));
                const float e = __expf(lg - m);
                float ssum = e;
#pragma unroll
                for (int mask = 16; mask >= 1; mask >>= 1)
                    ssum += __shfl_xor(ssum, mask);
                const float c = e / ssum;
#pragma unroll
                for (int o = 0; o < 8; ++o)
                    s_acc[bb][o] = fmaf(c, u[bb][o], s_acc[bb][o]);
            }
        }
    }

#pragma unroll
    for (int bb = 0; bb < 4; ++bb) {
        float* sp = Sout + ((size_t)(b0 + bq4 * 4 + bb) * NK + kk) * 16 + oh * 8;
#pragma unroll
        for (int o = 0; o < 8; ++o) atomicAdd(sp + o, s_acc[bb][o]);
    }
}

__global__ __launch_bounds__(256)
void squash_kernel(const float* __restrict__ S, float* __restrict__ Vout)
{
    const int idx = blockIdx.x * 256 + threadIdx.x;
    float val = S[idx];
    float sq = val * val;
#pragma unroll
    for (int mask = 8; mask >= 1; mask >>= 1) sq += __shfl_xor(sq, mask);
    const float sc = sqrtf(sq) / (1.0f + sq);
    Vout[idx] = val * sc;
}

extern "C" void kernel_launch(void* const* d_in, const int* in_sizes, int n_in,
                              void* d_out, int out_size, void* d_ws, size_t ws_size,
                              hipStream_t stream)
{
    const float* X  = (const float*)d_in[0];   // [64][2048][16]
    const float* Wg = (const float*)d_in[1];   // [2048][32][16][16]
    float* out = (float*)d_out;                // [64][32][16]

    const size_t WHU   = (size_t)2048 * 4096;       // u32
    const size_t XHU   = (size_t)64 * 2048 * 8;     // u32
    const size_t PARTU = (size_t)512 * 4096;        // u32 (f16-pair partials)
    const size_t need  = (WHU + XHU + PARTU) * 4 + 3 * 32768 * 4;  // ~44.5 MB

    const dim3 blk(256), pgrid(512), rgrid(256);

    if (ws_size >= need) {
        uint32_t* Wh   = (uint32_t*)d_ws;
        uint32_t* XT   = Wh + WHU;
        uint32_t* part = XT + XHU;
        float* s0      = (float*)(part + PARTU);
        float* v0      = s0 + 32768;
        float* v01     = v0 + 32768;

        conv_w<<<dim3(2048), blk, 0, stream>>>(Wg, Wh);
        conv_x<<<dim3(512),  blk, 0, stream>>>(X, XT);

        caps_pass_m<0><<<pgrid, blk, 0, stream>>>(XT, Wh, nullptr, part);
        caps_reduce<0><<<rgrid, blk, 0, stream>>>(part, nullptr, s0, v0);
        caps_pass_m<1><<<pgrid, blk, 0, stream>>>(XT, Wh, v0, part);
        caps_reduce<1><<<rgrid, blk, 0, stream>>>(part, s0, nullptr, v01);
        caps_pass_m<1><<<pgrid, blk, 0, stream>>>(XT, Wh, v01, part);
        caps_reduce<2><<<rgrid, blk, 0, stream>>>(part, nullptr, nullptr, out);
    } else {
        // fallback: f32 atomic path
        float* s0 = (float*)d_ws;
        float* s1 = s0 + 32768;
        float* s2 = s1 + 32768;
        hipMemsetAsync(d_ws, 0, (size_t)3 * 32768 * sizeof(float), stream);
        caps_pass_f32<0><<<dim3(1024), blk, 0, stream>>>(X, Wg, nullptr, nullptr, s0);
        caps_pass_f32<1><<<dim3(1024), blk, 0, stream>>>(X, Wg, s0, nullptr, s1);
        caps_pass_f32<2><<<dim3(1024), blk, 0, stream>>>(X, Wg, s0, s1, s2);
        squash_kernel<<<dim3(128), blk, 0, stream>>>(s2, out);
    }
}